// Round 10
// baseline (298.433 us; speedup 1.0000x reference)
//
#include <hip/hip_runtime.h>
#include <cstdint>
#include <cstddef>

#define TT 2048
#define CC 768
#define KK 5
#define PCAP 64   // candidate pool per wave per mode (expected ~8 used)

typedef __attribute__((ext_vector_type(8))) short short8;
typedef __attribute__((ext_vector_type(4))) short short4v;
typedef __attribute__((ext_vector_type(4))) float float4v;

struct PairTab { int sa[12]; int sb[12]; };
struct PairMap { int src[12]; int tr[12]; };

#define N_SELF_BLK (8 * 136)   // 8 slices x 136 upper-triangle 128x128 tiles
#define TP 132                 // padded LDS tile row (ushorts)

// ---------------- device RNG hash ----------------
__device__ __forceinline__ unsigned int mix_hash(unsigned int a, unsigned int b) {
  unsigned long long x = (((unsigned long long)a) << 32) | (unsigned long long)b;
  x ^= x >> 33; x *= 0xff51afd7ed558ccdULL;
  x ^= x >> 33; x *= 0xc4ceb9fe1a85ec53ULL;
  x ^= x >> 33;
  return (unsigned int)(x & 0xffffffffu);
}

__device__ __forceinline__ unsigned short f2bf(float x) {  // RNE fp32->bf16
  union { float f; unsigned int u; } v; v.f = x;
  unsigned int r = v.u + 0x7fffu + ((v.u >> 16) & 1u);
  return (unsigned short)(r >> 16);
}

__device__ __forceinline__ float bf2f(unsigned short u) {
  union { unsigned int i; float f; } v; v.i = ((unsigned int)u) << 16; return v.f;
}

__device__ __forceinline__ void gload_lds16(const void* g, void* l) {
  __builtin_amdgcn_global_load_lds(
      (const __attribute__((address_space(1))) unsigned int*)g,
      (__attribute__((address_space(3))) unsigned int*)l, 16, 0, 0);
}

__device__ __forceinline__ bool lexlt(float k1, int i1, float k2, int i2) {
  return k1 < k2 || (k1 == k2 && i1 < i2);
}

#define INS5(kk_, ii_, L)                                                        \
  if (lexlt(kk_, ii_, L##k[4], L##i[4])) {                                       \
    L##k[4] = kk_; L##i[4] = ii_;                                                \
    if (lexlt(L##k[4], L##i[4], L##k[3], L##i[3])) {                             \
      float tk = L##k[3]; int ti_ = L##i[3]; L##k[3] = L##k[4]; L##i[3] = L##i[4]; L##k[4] = tk; L##i[4] = ti_; \
      if (lexlt(L##k[3], L##i[3], L##k[2], L##i[2])) {                           \
        tk = L##k[2]; ti_ = L##i[2]; L##k[2] = L##k[3]; L##i[2] = L##i[3]; L##k[3] = tk; L##i[3] = ti_; \
        if (lexlt(L##k[2], L##i[2], L##k[1], L##i[1])) {                         \
          tk = L##k[1]; ti_ = L##i[1]; L##k[1] = L##k[2]; L##i[1] = L##i[2]; L##k[2] = tk; L##i[2] = ti_; \
          if (lexlt(L##k[1], L##i[1], L##k[0], L##i[0])) {                       \
            tk = L##k[0]; ti_ = L##i[0]; L##k[0] = L##k[1]; L##i[0] = L##i[1]; L##k[1] = tk; L##i[1] = ti_; \
          }                                                                      \
        }                                                                        \
      }                                                                          \
    }                                                                            \
  }

// ---------------- fused prep: fp32->bf16 + row sumsq/inv-norm + acc/ticket zeroing ----------------
// (summation order preserved exactly; do not restructure — sq/inv feed tie-sensitive argmins)
__global__ __launch_bounds__(192) void prep_kernel(const float* __restrict__ z1, const float* __restrict__ z2,
                                                   unsigned short* __restrict__ zb, float* __restrict__ sq,
                                                   float* __restrict__ inv, float* __restrict__ accs) {
  int r = blockIdx.x;  // 0..16383
  if (r == 0 && threadIdx.x < 64) accs[threadIdx.x] = 0.f;   // accs + last-block ticket
  const float* p = (r < 4 * TT) ? (z1 + (size_t)r * CC) : (z2 + (size_t)(r - 4 * TT) * CC);
  unsigned short* o = zb + (size_t)r * CC;
  float4 v = ((const float4*)p)[threadIdx.x];
  float s = v.x * v.x + v.y * v.y + v.z * v.z + v.w * v.w;
  ushort4 u;
  u.x = f2bf(v.x); u.y = f2bf(v.y); u.z = f2bf(v.z); u.w = f2bf(v.w);
  ((ushort4*)o)[threadIdx.x] = u;
#pragma unroll
  for (int off = 32; off > 0; off >>= 1) s += __shfl_down(s, off, 64);
  __shared__ float wred[3];
  int lane = threadIdx.x & 63, w = threadIdx.x >> 6;
  if (lane == 0) wred[w] = s;
  __syncthreads();
  if (threadIdx.x == 0) {
    float tot = wred[0] + wred[1] + wred[2];
    sq[r] = tot; inv[r] = rsqrtf(tot + 1e-12f);
  }
}

// ---------------- shared gram main loop: BK=64, XOR-swizzled LDS ----------------
// NOTE (rounds 4/6/7 post-mortems): (a) LDS must be a direct __shared__ decl in the calling
// __global__, passed at most ONE level (SmemKL& arg — round-5/9-proven); no nested-union refs.
// (b) acc stays acc[4][4] (64 regs) — fat accumulators halve occupancy and break the swizzle
// codegen. (c) NO cooperative/grid.sync structures (~100us/sync on 8-XCD MI355X).
struct SmemKL { unsigned short As[128 * 64]; unsigned short Bs[128 * 64]; };  // 32768 B

__device__ __forceinline__ void gram_mainloop(const unsigned short* __restrict__ A,
                                              const unsigned short* __restrict__ B,
                                              int bm, int bn, SmemKL& st, float4v (&acc)[4][4]) {
  const int lane = threadIdx.x & 63, waveId = threadIdx.x >> 6;
  const int wm = (waveId >> 1) * 64, wn = (waveId & 1) * 64;
  const int lrow = lane & 15, lquad = lane >> 4;
  for (int kk = 0; kk < CC; kk += 64) {
    // stage 128x64 per matrix; LDS slot l holds global chunk (l&7)^(row&7) -> swizzled (conflict-free)
#pragma unroll
    for (int c = 0; c < 4; ++c) {
      int l = c * 256 + threadIdx.x;        // 0..1023 chunks of 8 shorts
      int row = l >> 3, pc = l & 7;
      int sc = pc ^ (row & 7);
      gload_lds16(A + (size_t)(bm + row) * CC + kk + sc * 8, &st.As[l * 8]);
      gload_lds16(B + (size_t)(bn + row) * CC + kk + sc * 8, &st.Bs[l * 8]);
    }
    __syncthreads();
#pragma unroll
    for (int h = 0; h < 2; ++h) {
      short8 af[4], bfr[4];
#pragma unroll
      for (int i = 0; i < 4; ++i) {
        int ra = wm + i * 16 + lrow;
        int ca = (h * 4 + lquad) ^ (ra & 7);
        af[i] = *(const short8*)&st.As[ra * 64 + ca * 8];
        int rb = wn + i * 16 + lrow;
        int cb2 = (h * 4 + lquad) ^ (rb & 7);
        bfr[i] = *(const short8*)&st.Bs[rb * 64 + cb2 * 8];
      }
#pragma unroll
      for (int i = 0; i < 4; ++i)
#pragma unroll
        for (int j = 0; j < 4; ++j)
          acc[i][j] = __builtin_amdgcn_mfma_f32_16x16x32_bf16(af[i], bfr[j], acc[i][j], 0, 0, 0);
    }
    __syncthreads();
  }
}

// ---------------- fused gram: self tiles [0, N_SELF_BLK) then cross tiles ----------------
// Round-1/9-proven monolith pattern + T1 XCD-chunked blockIdx swizzle: physical block b (XCD
// b%8) processes logical tile (b%8)*(nblk/8)+b/8, so each XCD owns a CONTIGUOUS chunk of tiles
// -> A-panels fetched once per XCD (not 8x), pair B-slices (3MB) stay resident in one 4MB L2.
// Bijective because nblk = 1088 + 256*nU is always divisible by 8. Pure remap: zero numerics risk.
__global__ __launch_bounds__(256, 4) void gram_all(unsigned int crossN,
                                                   const unsigned short* __restrict__ zb,
                                                   unsigned short* __restrict__ gram,
                                                   const float* __restrict__ sqAll,
                                                   const float* __restrict__ invAll, PairTab tab,
                                                   float* __restrict__ prow_v, int* __restrict__ prow_i,
                                                   float* __restrict__ pcol_v, int* __restrict__ pcol_i,
                                                   float* __restrict__ pmin0, float* __restrict__ pmin1) {
  __shared__ union {
    SmemKL st;                        // K-loop staging (32768 B)
    unsigned short tile[128 * TP];    // self epilogue (33792 B)
  } sm;
  __shared__ union {
    struct { float sInvA[128]; float sInvB[128];
             float rowv[2][128]; int rowi[2][128];
             float colv[2][128]; int coli[2][128]; } c;     // cross epilogue (5120 B)
    struct { float sqN[128]; float invN[128]; float sqM[128]; float invM[128]; } s;  // self (2048 B)
  } ep;
  // total LDS 38912 B -> 4 blocks/CU (same as round-1 gram_all)

  const int nblk = N_SELF_BLK + (int)crossN;
  const int bid = ((int)blockIdx.x & 7) * (nblk >> 3) + ((int)blockIdx.x >> 3);  // T1 XCD chunking
  const bool isSelf = bid < N_SELF_BLK;
  int bm, bn, p = 0, s = 0;
  const unsigned short *A, *B;
  if (isSelf) {
    s = bid / 136;
    int t = bid % 136;
    int ti = 0;
    while (t >= 16 - ti) { t -= 16 - ti; ++ti; }
    int tj = ti + t;           // ti <= tj
    bm = ti * 128; bn = tj * 128;
    A = zb + (size_t)s * TT * CC;
    B = A;
    const float* sqS = sqAll + (size_t)s * TT;
    const float* invS = invAll + (size_t)s * TT;
    if (threadIdx.x < 128) { ep.s.sqN[threadIdx.x] = sqS[bn + threadIdx.x]; ep.s.invN[threadIdx.x] = invS[bn + threadIdx.x]; }
    else { ep.s.sqM[threadIdx.x - 128] = sqS[bm + threadIdx.x - 128]; ep.s.invM[threadIdx.x - 128] = invS[bm + threadIdx.x - 128]; }
  } else {
    int cb = bid - N_SELF_BLK;
    p = cb >> 8;
    int tile = cb & 255;
    bn = (tile & 15) * 128;
    bm = (tile >> 4) * 128;
    A = zb + (size_t)tab.sa[p] * TT * CC;
    B = zb + (size_t)tab.sb[p] * TT * CC;
    if (threadIdx.x < 128) ep.c.sInvA[threadIdx.x] = invAll[(size_t)tab.sa[p] * TT + bm + threadIdx.x];
    else ep.c.sInvB[threadIdx.x - 128] = invAll[(size_t)tab.sb[p] * TT + bn + threadIdx.x - 128];
  }

  float4v acc[4][4];
#pragma unroll
  for (int i = 0; i < 4; ++i)
#pragma unroll
    for (int j = 0; j < 4; ++j) acc[i][j] = (float4v){0.f, 0.f, 0.f, 0.f};

  gram_mainloop(A, B, bm, bn, sm.st, acc);

  const int lane = threadIdx.x & 63, waveId = threadIdx.x >> 6;
  const int wm = (waveId >> 1) * 64, wn = (waveId & 1) * 64;
  const int lrow = lane & 15, lquad = lane >> 4;

  if (isSelf) {
    // ---- scatter acc -> LDS tile as bf16 ----
#pragma unroll
    for (int i = 0; i < 4; ++i)
#pragma unroll
      for (int j = 0; j < 4; ++j)
#pragma unroll
        for (int r = 0; r < 4; ++r) {
          int lr = wm + i * 16 + lquad * 4 + r;
          int lc = wn + j * 16 + lrow;
          sm.tile[lr * TP + lc] = f2bf(acc[i][j][r]);
        }
    __syncthreads();
    unsigned short* G = gram + (size_t)s * TT * TT;
    // ---- direct rows: coalesced 8B stores from LDS ----
    for (int it = 0; it < 16; ++it) {
      int task = it * 256 + threadIdx.x;
      int r = task >> 5;          // 0..127
      int c = task & 31;          // chunk of 4 ushorts
      short4v v = *(const short4v*)&sm.tile[r * TP + c * 4];
      *(short4v*)&G[(size_t)(bm + r) * TT + bn + c * 4] = v;
    }
    // ---- mirror rows (offdiag): transposed LDS reads, coalesced 8B stores ----
    if (bm != bn) {
      for (int it = 0; it < 16; ++it) {
        int task = it * 256 + threadIdx.x;
        int cc = task >> 5;       // mirror row = original col 0..127
        int q = task & 31;        // chunk of 4 original rows
        short4v v;
        v[0] = (short)sm.tile[(q * 4 + 0) * TP + cc];
        v[1] = (short)sm.tile[(q * 4 + 1) * TP + cc];
        v[2] = (short)sm.tile[(q * 4 + 2) * TP + cc];
        v[3] = (short)sm.tile[(q * 4 + 3) * TP + cc];
        *(short4v*)&G[(size_t)(bn + cc) * TT + bm + q * 4] = v;
      }
    }
    // ---- per-slab min partials for top5 threshold (bf16 round-trip values, diag excluded) ----
    if (threadIdx.x < 128) {
      int r = threadIdx.x;
      float m0 = INFINITY, m1 = INFINITY;
      for (int c = 0; c < 128; ++c) {
        if (bm == bn && c == r) continue;
        float g = bf2f(sm.tile[r * TP + c]);
        m0 = fminf(m0, ep.s.sqN[c] - 2.f * g);
        m1 = fminf(m1, -g * ep.s.invN[c]);
      }
      pmin0[((size_t)s * 16 + (bn >> 7)) * TT + bm + r] = m0;
      pmin1[((size_t)s * 16 + (bn >> 7)) * TT + bm + r] = m1;
    } else if (bm != bn) {
      int c = threadIdx.x - 128;
      float m0 = INFINITY, m1 = INFINITY;
      for (int r = 0; r < 128; ++r) {
        float g = bf2f(sm.tile[r * TP + c]);
        m0 = fminf(m0, ep.s.sqM[r] - 2.f * g);
        m1 = fminf(m1, -g * ep.s.invM[r]);
      }
      pmin0[((size_t)s * 16 + (bm >> 7)) * TT + bn + c] = m0;
      pmin1[((size_t)s * 16 + (bm >> 7)) * TT + bn + c] = m1;
    }
    return;
  }

  // ---- cross: fused dual argmin partials ----
  float rbv[4][4]; int rbi[4][4];
#pragma unroll
  for (int i = 0; i < 4; ++i)
#pragma unroll
    for (int r = 0; r < 4; ++r) { rbv[i][r] = INFINITY; rbi[i][r] = TT; }
#pragma unroll
  for (int i = 0; i < 4; ++i)
#pragma unroll
    for (int j = 0; j < 4; ++j) {
      int col = bn + wn + j * 16 + lrow;
      float ivb = ep.c.sInvB[wn + j * 16 + lrow];
#pragma unroll
      for (int r = 0; r < 4; ++r) {
        float v = -acc[i][j][r] * ivb;
        if (v < rbv[i][r]) { rbv[i][r] = v; rbi[i][r] = col; }
      }
    }
#pragma unroll
  for (int m = 1; m <= 8; m <<= 1) {
#pragma unroll
    for (int i = 0; i < 4; ++i)
#pragma unroll
      for (int r = 0; r < 4; ++r) {
        float v2 = __shfl_xor(rbv[i][r], m, 64);
        int i2 = __shfl_xor(rbi[i][r], m, 64);
        if (v2 < rbv[i][r] || (v2 == rbv[i][r] && i2 < rbi[i][r])) { rbv[i][r] = v2; rbi[i][r] = i2; }
      }
  }
  if (lrow == 0) {
#pragma unroll
    for (int i = 0; i < 4; ++i)
#pragma unroll
      for (int r = 0; r < 4; ++r) {
        int lr = wm + i * 16 + lquad * 4 + r;
        ep.c.rowv[wn >> 6][lr] = rbv[i][r]; ep.c.rowi[wn >> 6][lr] = rbi[i][r];
      }
  }

  float cbv[4]; int cbi[4];
#pragma unroll
  for (int j = 0; j < 4; ++j) { cbv[j] = INFINITY; cbi[j] = TT; }
#pragma unroll
  for (int j = 0; j < 4; ++j)
#pragma unroll
    for (int i = 0; i < 4; ++i)
#pragma unroll
      for (int r = 0; r < 4; ++r) {
        int lr = wm + i * 16 + lquad * 4 + r;
        float v = -acc[i][j][r] * ep.c.sInvA[lr];
        if (v < cbv[j]) { cbv[j] = v; cbi[j] = bm + lr; }
      }
#pragma unroll
  for (int m = 16; m <= 32; m <<= 1) {
#pragma unroll
    for (int j = 0; j < 4; ++j) {
      float v2 = __shfl_xor(cbv[j], m, 64);
      int i2 = __shfl_xor(cbi[j], m, 64);
      if (v2 < cbv[j] || (v2 == cbv[j] && i2 < cbi[j])) { cbv[j] = v2; cbi[j] = i2; }
    }
  }
  if (lquad == 0) {
#pragma unroll
    for (int j = 0; j < 4; ++j) {
      int lc = wn + j * 16 + lrow;
      ep.c.colv[wm >> 6][lc] = cbv[j]; ep.c.coli[wm >> 6][lc] = cbi[j];
    }
  }
  __syncthreads();

  int bj = bn >> 7, bi2 = bm >> 7;
  if (threadIdx.x < 128) {
    int t = threadIdx.x;
    float v0 = ep.c.rowv[0][t], v1 = ep.c.rowv[1][t];
    int i0 = ep.c.rowi[0][t], i1 = ep.c.rowi[1][t];
    bool take1 = (v1 < v0) || (v1 == v0 && i1 < i0);
    prow_v[((size_t)p * 16 + bj) * TT + bm + t] = take1 ? v1 : v0;
    prow_i[((size_t)p * 16 + bj) * TT + bm + t] = take1 ? i1 : i0;
  } else {
    int t = threadIdx.x - 128;
    float v0 = ep.c.colv[0][t], v1 = ep.c.colv[1][t];
    int i0 = ep.c.coli[0][t], i1 = ep.c.coli[1][t];
    bool take1 = (v1 < v0) || (v1 == v0 && i1 < i0);
    pcol_v[((size_t)p * 16 + bi2) * TT + bn + t] = take1 ? v1 : v0;
    pcol_i[((size_t)p * 16 + bi2) * TT + bn + t] = take1 ? i1 : i0;
  }
}

// ---------------- fallback: full INS5 scan for one row (exact; correctness guard) ----------------
__device__ void top5_row_full(const unsigned short* __restrict__ G, const float* __restrict__ sq,
                              const float* __restrict__ inv, int i, int lane,
                              int* __restrict__ o0, int* __restrict__ o1) {
  float ak[5]; int ai[5];
  float bk[5]; int bi[5];
#pragma unroll
  for (int t = 0; t < 5; ++t) { ak[t] = INFINITY; ai[t] = TT; bk[t] = INFINITY; bi[t] = TT; }
#pragma unroll
  for (int step = 0; step < 8; ++step) {
    int j4 = (step * 64 + lane) * 4;
    ushort4 g4u = *(const ushort4*)&G[j4];
    float4 s4 = *(const float4*)&sq[j4];
    float4 v4 = *(const float4*)&inv[j4];
#pragma unroll
    for (int c = 0; c < 4; ++c) {
      int j = j4 + c;
      float g = bf2f((c == 0) ? g4u.x : (c == 1) ? g4u.y : (c == 2) ? g4u.z : g4u.w);
      float sv = (c == 0) ? s4.x : (c == 1) ? s4.y : (c == 2) ? s4.z : s4.w;
      float iv = (c == 0) ? v4.x : (c == 1) ? v4.y : (c == 2) ? v4.z : v4.w;
      float k0 = (j == i) ? INFINITY : sv - 2.f * g;
      float k1 = (j == i) ? INFINITY : -g * iv;
      INS5(k0, j, a)
      INS5(k1, j, b)
    }
  }
#pragma unroll
  for (int m = 1; m <= 32; m <<= 1) {
    float ok[5]; int oi[5];
#pragma unroll
    for (int t = 0; t < 5; ++t) { ok[t] = __shfl_xor(ak[t], m, 64); oi[t] = __shfl_xor(ai[t], m, 64); }
#pragma unroll
    for (int t = 0; t < 5; ++t) { INS5(ok[t], oi[t], a) }
#pragma unroll
    for (int t = 0; t < 5; ++t) { ok[t] = __shfl_xor(bk[t], m, 64); oi[t] = __shfl_xor(bi[t], m, 64); }
#pragma unroll
    for (int t = 0; t < 5; ++t) { INS5(ok[t], oi[t], b) }
  }
  if (lane < KK) {
    int v0 = (lane == 0) ? ai[0] : (lane == 1) ? ai[1] : (lane == 2) ? ai[2] : (lane == 3) ? ai[3] : ai[4];
    int v1 = (lane == 0) ? bi[0] : (lane == 1) ? bi[1] : (lane == 2) ? bi[2] : (lane == 3) ? bi[3] : bi[4];
    o0[lane] = v0;
    o1[lane] = v1;
  }
}

// ---------------- single-pass dual top-5: slab-skipping threshold scan ----------------
__device__ void top5_body(int s, int bx, const unsigned short* __restrict__ gram,
                          const float* __restrict__ sqAll, const float* __restrict__ invAll,
                          const float* __restrict__ pmin0, const float* __restrict__ pmin1,
                          int* __restrict__ out0, int* __restrict__ out1) {
  int w = threadIdx.x >> 6, lane = threadIdx.x & 63;
  int i = bx * 4 + w;
  const unsigned short* G = gram + (size_t)s * TT * TT + (size_t)i * TT;
  const float* sq = sqAll + (size_t)s * TT;
  const float* inv = invAll + (size_t)s * TT;

  __shared__ float pvv[4][2][PCAP];
  __shared__ int pix[4][2][PCAP];
  __shared__ int pcnt[4][2];
  if (lane < 2) pcnt[w][lane] = 0;

  // ---- threshold: rank-4 (5th smallest) of 16 slab mins, per mode ----
  int t16 = lane & 15;
  float m0 = pmin0[((size_t)s * 16 + t16) * TT + i];
  float m1 = pmin1[((size_t)s * 16 + t16) * TT + i];
  int r0 = 0, r1 = 0;
#pragma unroll
  for (int d = 1; d < 16; ++d) {
    int h = (t16 + d) & 15;
    int src = (lane & 48) | h;
    float o0 = __shfl(m0, src, 64);
    float o1 = __shfl(m1, src, 64);
    r0 += (o0 < m0 || (o0 == m0 && h < t16)) ? 1 : 0;
    r1 += (o1 < m1 || (o1 == m1 && h < t16)) ? 1 : 0;
  }
  unsigned long long b0 = __ballot(r0 == 4);
  unsigned long long b1 = __ballot(r1 == 4);
  float T0 = __shfl(m0, (int)(__ffsll(b0) - 1), 64);
  float T1 = __shfl(m1, (int)(__ffsll(b1) - 1), 64);

  // slab masks (bits 0..15 of ballots; lanes 16+ are copies)
  unsigned int sl0 = (unsigned int)(__ballot(m0 <= T0) & 0xFFFFull);
  unsigned int sl1 = (unsigned int)(__ballot(m1 <= T1) & 0xFFFFull);
  unsigned int slmask = sl0 | sl1;

  // ---- scan only qualifying slabs (128 cols each, 2 per lane) ----
  while (slmask) {
    int sb = __ffs(slmask) - 1;
    slmask &= slmask - 1;
    int j2 = sb * 128 + lane * 2;
    ushort2 g2 = *(const ushort2*)&G[j2];
    float2 s2 = *(const float2*)&sq[j2];
    float2 v2 = *(const float2*)&inv[j2];
#pragma unroll
    for (int c = 0; c < 2; ++c) {
      int j = j2 + c;
      float g = bf2f((c == 0) ? g2.x : g2.y);
      float sv = (c == 0) ? s2.x : s2.y;
      float iv = (c == 0) ? v2.x : v2.y;
      float k0 = (j == i) ? INFINITY : sv - 2.f * g;
      float k1 = (j == i) ? INFINITY : -g * iv;
      bool c0 = (k0 <= T0), c1 = (k1 <= T1);
      if (__any(c0)) {
        if (c0) {
          int q = atomicAdd(&pcnt[w][0], 1);
          if (q < PCAP) { pvv[w][0][q] = k0; pix[w][0][q] = j; }
        }
      }
      if (__any(c1)) {
        if (c1) {
          int q = atomicAdd(&pcnt[w][1], 1);
          if (q < PCAP) { pvv[w][1][q] = k1; pix[w][1][q] = j; }
        }
      }
    }
  }

  int c0n = pcnt[w][0], c1n = pcnt[w][1];
  if (c0n > PCAP || c1n > PCAP || c0n < KK || c1n < KK) {
    // overflow or (bug-guard) underflow -> exact full scan
    top5_row_full(G, sq, inv, i, lane,
                  out0 + ((size_t)s * TT + i) * KK, out1 + ((size_t)s * TT + i) * KK);
    return;
  }
  // ---- final: exact lexicographic rank of candidates (<= 64, one per lane) ----
  {
    float cv = (lane < c0n) ? pvv[w][0][lane] : INFINITY;
    int ci = (lane < c0n) ? pix[w][0][lane] : TT;
    int r = 0;
    for (int t = 0; t < c0n; ++t) {
      float ov = pvv[w][0][t]; int oi = pix[w][0][t];
      r += lexlt(ov, oi, cv, ci) ? 1 : 0;
    }
    if (lane < c0n && r < KK) out0[((size_t)s * TT + i) * KK + r] = ci;
  }
  {
    float cv = (lane < c1n) ? pvv[w][1][lane] : INFINITY;
    int ci = (lane < c1n) ? pix[w][1][lane] : TT;
    int r = 0;
    for (int t = 0; t < c1n; ++t) {
      float ov = pvv[w][1][t]; int oi = pix[w][1][t];
      r += lexlt(ov, oi, cv, ci) ? 1 : 0;
    }
    if (lane < c1n && r < KK) out1[((size_t)s * TT + i) * KK + r] = ci;
  }
}

// ---------------- argmin stage 2 body (with transpose-dedup remap) ----------------
__device__ void argmin_body(int bx, int p, const float* __restrict__ prow_v, const int* __restrict__ prow_i,
                            const float* __restrict__ pcol_v, const int* __restrict__ pcol_i,
                            const PairMap& pm,
                            int* __restrict__ b_of_a, int* __restrict__ a_of_b) {
  int u = pm.src[p];                   // unique gram pair that was computed
  bool tr = pm.tr[p] != 0;             // this pair's D is the transpose of pair u's D
  int t = bx * 256 + threadIdx.x;
  int isRow = t < TT;
  int x = isRow ? t : t - TT;
  bool useRow = (isRow != 0) != tr;
  const float* pv = (useRow ? prow_v : pcol_v) + (size_t)u * 16 * TT;
  const int* pi = (useRow ? prow_i : pcol_i) + (size_t)u * 16 * TT;
  float best = INFINITY; int bidx = TT;
  for (int s = 0; s < 16; ++s) {
    float v = pv[(size_t)s * TT + x]; int id = pi[(size_t)s * TT + x];
    if (v < best || (v == best && id < bidx)) { best = v; bidx = id; }
  }
  if (isRow) b_of_a[(size_t)p * TT + x] = bidx;
  else       a_of_b[(size_t)p * TT + x] = bidx;
}

// ---------------- fused top5 + argmin stage 2 ----------------
__global__ __launch_bounds__(256) void top5_argmin_fused(const unsigned short* __restrict__ gram,
                                                         const float* __restrict__ sqAll,
                                                         const float* __restrict__ invAll,
                                                         const float* __restrict__ pmin0,
                                                         const float* __restrict__ pmin1,
                                                         int* __restrict__ out0, int* __restrict__ out1,
                                                         const float* __restrict__ prow_v, const int* __restrict__ prow_i,
                                                         const float* __restrict__ pcol_v, const int* __restrict__ pcol_i,
                                                         PairMap pm,
                                                         int* __restrict__ b_of_a, int* __restrict__ a_of_b) {
  unsigned int b = blockIdx.x;
  if (b < 4096) {                                  // top5: was dim3(512, 8)
    top5_body((int)(b >> 9), (int)(b & 511), gram, sqAll, invAll, pmin0, pmin1, out0, out1);
  } else {                                         // argmin: was dim3(16, 12)
    unsigned int t = b - 4096;
    argmin_body((int)(t & 15), (int)(t >> 4), prow_v, prow_i, pcol_v, pcol_i, pm, b_of_a, a_of_b);
  }
}

// ---------------- crossbrain hinge body: 64 rows/block, 1 atomic/block ----------------
__device__ void cb_hinge_body(int bx, int c, const unsigned short* __restrict__ gram, const float* __restrict__ invAll,
                              const int* __restrict__ neigh1, float* __restrict__ cb_acc) {
  int i0 = bx * 64;
  int sa = c, sb = (c < 4) ? (c + 4) : (c - 4);
  const unsigned short* Gs = gram + (size_t)sb * TT * TT;
  const float* invB = invAll + (size_t)sb * TT;
  const int* neighA = neigh1 + (size_t)sa * TT * KK;
  unsigned int seed = 0x13579BDFu + 0x9E3779B9u * (unsigned)c;
  int tid = threadIdx.x;

  __shared__ int targ[64][10];
  __shared__ float sval[64][10];
  for (int t = tid; t < 64 * KK; t += 256) targ[t / KK][t % KK] = neighA[(size_t)i0 * KK + t];
  __syncthreads();
  if (tid < 64) {
    int i = i0 + tid;
    int pos[KK];
#pragma unroll
    for (int k = 0; k < KK; ++k) pos[k] = targ[tid][k];
    unsigned int ctr = 0;
    for (int k = 0; k < KK; ++k) {
      int cand;
      while (true) {
        unsigned int h = mix_hash(seed ^ (unsigned)i, ctr++);
        cand = (int)(h & (TT - 1));
        bool bad = (cand == i);
        for (int t = 0; t < KK; ++t) bad = bad || (cand == pos[t]);
        for (int t = 0; t < k; ++t) bad = bad || (cand == targ[tid][KK + t]);
        if (!bad) break;
      }
      targ[tid][KK + k] = cand;
    }
  }
  __syncthreads();
  for (int t = tid; t < 640; t += 256) {
    int il = t / 10, k = t % 10;
    int tt = targ[il][k];
    sval[il][k] = bf2f(Gs[(size_t)(i0 + il) * TT + tt]) * invB[tt];
  }
  __syncthreads();
  if (tid < 64) {
    int i = i0 + tid;
    float ii = invB[i];
    const float lo = -1.f + 1e-8f, hi = 1.f - 1e-8f;
    float hsum = 0.f;
#pragma unroll
    for (int k = 0; k < KK; ++k) {
      float sp = fminf(fmaxf(sval[tid][k] * ii, lo), hi);
      float sn = fminf(fmaxf(sval[tid][KK + k] * ii, lo), hi);
      float h = sn - sp + 0.05f;
      hsum += (h > 0.f) ? h : 0.f;
    }
#pragma unroll
    for (int off = 32; off > 0; off >>= 1) hsum += __shfl_down(hsum, off, 64);
    if (tid == 0) atomicAdd(&cb_acc[c], hsum);
  }
}

// ---------------- mutual matching body ----------------
__device__ void mutual_body(int p, const int* __restrict__ b_of_a_all,
                            const int* __restrict__ a_of_b_all,
                            int* __restrict__ idxB_all, int* __restrict__ matchedB_all,
                            int* __restrict__ unmatched_all, int* __restrict__ scalars_all) {
  const int* b_of_a = b_of_a_all + (size_t)p * TT;
  const int* a_of_b = a_of_b_all + (size_t)p * TT;
  int* idxB_of_A = idxB_all + (size_t)p * TT;
  int* matchedB = matchedB_all + (size_t)p * TT;
  int* unmatched = unmatched_all + (size_t)p * TT;
  __shared__ int cnt_sh;
  for (int j = threadIdx.x; j < TT; j += 256) matchedB[j] = 0;
  __syncthreads();
  for (int i = threadIdx.x; i < TT; i += 256) {
    int b = b_of_a[i];
    bool mut = (a_of_b[b] == i);
    idxB_of_A[i] = mut ? b : -1;
    if (mut) matchedB[b] = 1;
  }
  __syncthreads();
  if (threadIdx.x == 0) cnt_sh = 0;
  __syncthreads();
  for (int j = threadIdx.x; j < TT; j += 256) {
    if (!matchedB[j]) { int q = atomicAdd(&cnt_sh, 1); unmatched[q] = j; }
  }
  __syncthreads();
  if (threadIdx.x == 0) {
    int c = cnt_sh;
    if (c == 0) { unmatched[0] = 0; c = 1; }
    scalars_all[p * 16] = c;
  }
}

// ---------------- fused cb_hinge + mutual ----------------
__global__ __launch_bounds__(256) void cb_mutual_fused(const unsigned short* __restrict__ gram,
                                                       const float* __restrict__ invAll,
                                                       const int* __restrict__ neigh1, float* __restrict__ cb_acc,
                                                       const int* __restrict__ b_of_a, const int* __restrict__ a_of_b,
                                                       int* __restrict__ idxB_all, int* __restrict__ matchedB_all,
                                                       int* __restrict__ unmatched_all, int* __restrict__ scalars_all) {
  unsigned int b = blockIdx.x;
  if (b < 256) {                                   // cb: was dim3(32, 8)
    cb_hinge_body((int)(b & 31), (int)(b >> 5), gram, invAll, neigh1, cb_acc);
  } else {                                         // mutual: was <<<12>>>
    mutual_body((int)(b - 256), b_of_a, a_of_b, idxB_all, matchedB_all, unmatched_all, scalars_all);
  }
}

// ---------------- NRC hinge + last-block final combine ----------------
// accs layout: [0..7]=cb_acc, [8..31]=nrc_acc (12 pairs x {sum,cnt}), [32]=ticket (uint).
__global__ __launch_bounds__(256) void nrc_hinge_block(const unsigned short* __restrict__ gram, const float* __restrict__ invAll,
                                                       const int* __restrict__ neighC, const int* __restrict__ idxB_all,
                                                       const int* __restrict__ unmatched_all,
                                                       const int* __restrict__ scalars_all,
                                                       PairTab tab, float* __restrict__ accs,
                                                       float* __restrict__ out) {
  int p = blockIdx.y;
  int i0 = blockIdx.x * 64;
  int sa = tab.sa[p], sb = tab.sb[p];
  const unsigned short* Gs = gram + (size_t)sb * TT * TT;
  const float* invB = invAll + (size_t)sb * TT;
  const int* neighA = neighC + (size_t)sa * TT * KK;
  const int* idxB_of_A = idxB_all + (size_t)p * TT;
  const int* unmatched = unmatched_all + (size_t)p * TT;
  unsigned int seed = 0xC0FFEE11u + 0x9E3779B9u * (unsigned)p;
  float* nrc_acc = accs + 8;
  float* acc = nrc_acc + p * 2;
  int tid = threadIdx.x;

  __shared__ int targ[64][10];
  __shared__ float sval[64][10];
  __shared__ unsigned int tmask[64];
  __shared__ int su[64];
  if (tid < 64) { tmask[tid] = 0; su[tid] = idxB_of_A[i0 + tid]; }
  __syncthreads();
  unsigned int neg_count = (unsigned int)scalars_all[p * 16];
  for (int t = tid; t < 64 * KK; t += 256) {
    int il = t / KK, k = t % KK;
    int nb = neighA[(size_t)i0 * KK + t];
    int pb = idxB_of_A[nb];
    targ[il][k] = (pb >= 0) ? pb : 0;
    if (pb >= 0) atomicOr(&tmask[il], 1u << k);
  }
  for (int t = tid; t < 64 * KK; t += 256) {
    int il = t / KK, k = t % KK;
    int i = i0 + il;
    unsigned int r = mix_hash(seed ^ 0xA5A5u, (unsigned)(i * KK + k)) & (TT - 1);
    targ[il][KK + k] = unmatched[r % neg_count];
  }
  __syncthreads();
  for (int t = tid; t < 640; t += 256) {
    int il = t / 10, k = t % 10;
    int u = su[il] >= 0 ? su[il] : 0;
    int tt = targ[il][k];
    sval[il][k] = bf2f(Gs[(size_t)u * TT + tt]) * invB[tt];
  }
  __syncthreads();
  if (tid < 64) {
    int idx = su[tid];
    int u = idx >= 0 ? idx : 0;
    float iu = invB[u];
    unsigned int tm = tmask[tid];
    float hsum = 0.f; int pcnt = 0;
#pragma unroll
    for (int k = 0; k < KK; ++k) {
      if (tm & (1u << k)) {
        float dpos = 1.f - sval[tid][k] * iu;
        float dneg = 1.f - sval[tid][KK + k] * iu;
        float h = dpos - dneg + 0.4f;
        hsum += (h > 0.f) ? h : 0.f;
        pcnt++;
      }
    }
    float hs = 0.f, vc = 0.f;
    if (idx >= 0 && pcnt > 0) { hs = hsum / (float)pcnt; vc = 1.0f; }
#pragma unroll
    for (int off = 32; off > 0; off >>= 1) {
      hs += __shfl_down(hs, off, 64);
      vc += __shfl_down(vc, off, 64);
    }
    if (tid == 0) {
      atomicAdd(&acc[0], hs);
      atomicAdd(&acc[1], vc);
      // last-block ticket: final combine without a separate launch
      __threadfence();
      unsigned int old = atomicAdd((unsigned int*)(accs + 32), 1u);
      if (old == 32u * 12u - 1u) {
        const float* cb_acc = accs;
        float loss2 = 0.f;
        for (int c = 0; c < 8; ++c) loss2 += cb_acc[c] * (1.0f / 10240.0f);
        loss2 *= 0.25f;
        float loss3 = 0.f;
        for (int d = 0; d < 2; ++d) {
          float sx = 0.f;
          for (int t = 0; t < 6; ++t) {
            float cnt = nrc_acc[(d * 6 + t) * 2 + 1];
            float sum = nrc_acc[(d * 6 + t) * 2 + 0];
            sx += (cnt > 0.f) ? (sum / cnt) : 0.f;
          }
          loss3 += sx * (1.f / 6.f);
        }
        out[0] = 10.f * loss2 + 10.f * loss3;
      }
    }
  }
}

// ---------------- host-side numpy RandomState(seed).permutation(12)[:6] ----------------
namespace {
struct MT19937 {
  uint32_t mt[624]; int mti;
  void seed(uint32_t s) {
    mt[0] = s;
    for (int i = 1; i < 624; ++i) mt[i] = 1812433253u * (mt[i - 1] ^ (mt[i - 1] >> 30)) + (uint32_t)i;
    mti = 624;
  }
  uint32_t next() {
    if (mti >= 624) {
      for (int i = 0; i < 624; ++i) {
        uint32_t y = (mt[i] & 0x80000000u) | (mt[(i + 1) % 624] & 0x7fffffffu);
        uint32_t v = y >> 1;
        if (y & 1u) v ^= 0x9908b0dfu;
        mt[i] = mt[(i + 397) % 624] ^ v;
      }
      mti = 0;
    }
    uint32_t y = mt[mti++];
    y ^= y >> 11; y ^= (y << 7) & 0x9d2c5680u; y ^= (y << 15) & 0xefc60000u; y ^= y >> 18;
    return y;
  }
  uint32_t interval(uint32_t mx) {
    uint32_t mask = mx;
    mask |= mask >> 1; mask |= mask >> 2; mask |= mask >> 4; mask |= mask >> 8; mask |= mask >> 16;
    while (true) { uint32_t v = next() & mask; if (v <= mx) return v; }
  }
};
inline void np_perm12_first6(uint32_t seed, int* sel6) {
  int a[12]; for (int i = 0; i < 12; ++i) a[i] = i;
  MT19937 r; r.seed(seed);
  for (int i = 11; i >= 1; --i) { uint32_t j = r.interval((uint32_t)i); int t = a[i]; a[i] = a[j]; a[j] = t; }
  for (int i = 0; i < 6; ++i) sel6[i] = a[i];
}
}  // namespace

extern "C" void kernel_launch(void* const* d_in, const int* in_sizes, int n_in,
                              void* d_out, int out_size, void* d_ws, size_t ws_size,
                              hipStream_t stream) {
  const float* z1 = (const float*)d_in[0];
  const float* z2 = (const float*)d_in[1];
  float* out = (float*)d_out;

  char* base = (char*)d_ws;
  size_t off = 0;
  auto alloc = [&](size_t bytes) -> void* {
    void* p = base + off;
    off = (off + bytes + 255) & ~(size_t)255;
    return p;
  };
  unsigned short* gram   = (unsigned short*)alloc((size_t)8 * TT * TT * 2);  // 67 MB bf16 self grams
  unsigned short* zb     = (unsigned short*)alloc((size_t)8 * TT * CC * 2);
  float* sq              = (float*)alloc((size_t)8 * TT * 4);
  float* inv             = (float*)alloc((size_t)8 * TT * 4);
  int*   neigh1          = (int*)alloc((size_t)8 * TT * KK * 4);
  int*   neighC          = (int*)alloc((size_t)8 * TT * KK * 4);
  float* pmin0           = (float*)alloc((size_t)8 * 16 * TT * 4);   // per-slab row/col mins, mode0
  float* pmin1           = (float*)alloc((size_t)8 * 16 * TT * 4);   // mode1
  float* prow_v          = (float*)alloc((size_t)12 * 16 * TT * 4);
  int*   prow_i          = (int*)alloc((size_t)12 * 16 * TT * 4);
  float* pcol_v          = (float*)alloc((size_t)12 * 16 * TT * 4);
  int*   pcol_i          = (int*)alloc((size_t)12 * 16 * TT * 4);
  int*   b_of_a          = (int*)alloc((size_t)12 * TT * 4);
  int*   a_of_b          = (int*)alloc((size_t)12 * TT * 4);
  int*   idxB            = (int*)alloc((size_t)12 * TT * 4);
  int*   matchedB        = (int*)alloc((size_t)12 * TT * 4);
  int*   unmatched       = (int*)alloc((size_t)12 * TT * 4);
  int*   scalars         = (int*)alloc(12 * 16 * 4);
  float* accs            = (float*)alloc(64 * 4);
  float* cb_acc          = accs;

  // NRC pair selection (numpy RandomState(seed).permutation(12)[:6])
  int sel0[6], sel1[6];
  np_perm12_first6(0u, sel0);
  np_perm12_first6(1u, sel1);
  static const int PP[12] = {0, 0, 0, 1, 1, 1, 2, 2, 2, 3, 3, 3};
  static const int QQ[12] = {1, 2, 3, 0, 2, 3, 0, 1, 3, 0, 1, 2};
  PairTab tab;
  for (int d = 0; d < 2; ++d) {
    const int* sel = (d == 0) ? sel0 : sel1;
    for (int t = 0; t < 6; ++t) {
      int pi_ = PP[sel[t]], qi = QQ[sel[t]];
      int p = d * 6 + t;
      tab.sa[p] = (d == 0) ? pi_ : 4 + pi_;
      tab.sb[p] = (d == 0) ? 4 + qi : qi;
    }
  }

  // transpose-dedup (zero hits for these seeds but harmless)
  PairTab gtab; PairMap pm; int nU = 0;
  for (int p = 0; p < 12; ++p) {
    int f = -1, ftr = 0;
    for (int q = 0; q < nU; ++q) {
      if (gtab.sa[q] == tab.sb[p] && gtab.sb[q] == tab.sa[p]) { f = q; ftr = 1; break; }
      if (gtab.sa[q] == tab.sa[p] && gtab.sb[q] == tab.sb[p]) { f = q; ftr = 0; break; }
    }
    if (f >= 0) { pm.src[p] = f; pm.tr[p] = ftr; }
    else { gtab.sa[nU] = tab.sa[p]; gtab.sb[nU] = tab.sb[p]; pm.src[p] = nU; pm.tr[p] = 0; ++nU; }
  }

  // fused prep (bf16 convert + norms + acc/ticket zeroing)
  prep_kernel<<<8 * TT, 192, 0, stream>>>(z1, z2, zb, sq, inv, accs);

  // fused gram (self then cross), T1 XCD-chunked block swizzle inside the kernel
  unsigned int crossN = (unsigned int)(nU * 256);
  gram_all<<<N_SELF_BLK + crossN, 256, 0, stream>>>(crossN, zb, gram, sq, inv, gtab,
                                                    prow_v, prow_i, pcol_v, pcol_i, pmin0, pmin1);

  // fused top5 (slab-skipping threshold scan) + argmin stage 2
  top5_argmin_fused<<<4096 + 192, 256, 0, stream>>>(gram, sq, inv, pmin0, pmin1, neigh1, neighC,
                                                    prow_v, prow_i, pcol_v, pcol_i, pm, b_of_a, a_of_b);

  // fused cb_hinge + mutual matching
  cb_mutual_fused<<<256 + 12, 256, 0, stream>>>(gram, inv, neigh1, cb_acc,
                                                b_of_a, a_of_b, idxB, matchedB, unmatched, scalars);

  // nrc hinge with folded last-block final combine
  nrc_hinge_block<<<dim3(TT / 64, 12), 256, 0, stream>>>(gram, inv, neighC, idxB, unmatched, scalars,
                                                         tab, accs, out);
}

// Round 11
// 281.602 us; speedup vs baseline: 1.0598x; 1.0598x over previous
//
#include <hip/hip_runtime.h>
#include <cstdint>
#include <cstddef>

#define TT 2048
#define CC 768
#define KK 5
#define PCAP 64   // candidate pool per wave per mode (expected ~8 used)

typedef __attribute__((ext_vector_type(8))) short short8;
typedef __attribute__((ext_vector_type(4))) short short4v;
typedef __attribute__((ext_vector_type(4))) float float4v;

struct PairTab { int sa[12]; int sb[12]; };
struct PairMap { int src[12]; int tr[12]; };

#define N_SELF_BLK (8 * 136)   // 8 slices x 136 upper-triangle 128x128 tiles
#define TP 132                 // padded LDS tile row (ushorts)

// ---------------- device RNG hash ----------------
__device__ __forceinline__ unsigned int mix_hash(unsigned int a, unsigned int b) {
  unsigned long long x = (((unsigned long long)a) << 32) | (unsigned long long)b;
  x ^= x >> 33; x *= 0xff51afd7ed558ccdULL;
  x ^= x >> 33; x *= 0xc4ceb9fe1a85ec53ULL;
  x ^= x >> 33;
  return (unsigned int)(x & 0xffffffffu);
}

__device__ __forceinline__ unsigned short f2bf(float x) {  // RNE fp32->bf16
  union { float f; unsigned int u; } v; v.f = x;
  unsigned int r = v.u + 0x7fffu + ((v.u >> 16) & 1u);
  return (unsigned short)(r >> 16);
}

__device__ __forceinline__ float bf2f(unsigned short u) {
  union { unsigned int i; float f; } v; v.i = ((unsigned int)u) << 16; return v.f;
}

__device__ __forceinline__ void gload_lds16(const void* g, void* l) {
  __builtin_amdgcn_global_load_lds(
      (const __attribute__((address_space(1))) unsigned int*)g,
      (__attribute__((address_space(3))) unsigned int*)l, 16, 0, 0);
}

__device__ __forceinline__ bool lexlt(float k1, int i1, float k2, int i2) {
  return k1 < k2 || (k1 == k2 && i1 < i2);
}

#define INS5(kk_, ii_, L)                                                        \
  if (lexlt(kk_, ii_, L##k[4], L##i[4])) {                                       \
    L##k[4] = kk_; L##i[4] = ii_;                                                \
    if (lexlt(L##k[4], L##i[4], L##k[3], L##i[3])) {                             \
      float tk = L##k[3]; int ti_ = L##i[3]; L##k[3] = L##k[4]; L##i[3] = L##i[4]; L##k[4] = tk; L##i[4] = ti_; \
      if (lexlt(L##k[3], L##i[3], L##k[2], L##i[2])) {                           \
        tk = L##k[2]; ti_ = L##i[2]; L##k[2] = L##k[3]; L##i[2] = L##i[3]; L##k[3] = tk; L##i[3] = ti_; \
        if (lexlt(L##k[2], L##i[2], L##k[1], L##i[1])) {                         \
          tk = L##k[1]; ti_ = L##i[1]; L##k[1] = L##k[2]; L##i[1] = L##i[2]; L##k[2] = tk; L##i[2] = ti_; \
          if (lexlt(L##k[1], L##i[1], L##k[0], L##i[0])) {                       \
            tk = L##k[0]; ti_ = L##i[0]; L##k[0] = L##k[1]; L##i[0] = L##i[1]; L##k[1] = tk; L##i[1] = ti_; \
          }                                                                      \
        }                                                                        \
      }                                                                          \
    }                                                                            \
  }

// ---------------- fused prep: fp32->bf16 + row sumsq/inv-norm + acc/ticket zeroing ----------------
// (summation order preserved exactly; do not restructure — sq/inv feed tie-sensitive argmins)
__global__ __launch_bounds__(192) void prep_kernel(const float* __restrict__ z1, const float* __restrict__ z2,
                                                   unsigned short* __restrict__ zb, float* __restrict__ sq,
                                                   float* __restrict__ inv, float* __restrict__ accs) {
  int r = blockIdx.x;  // 0..16383
  if (r == 0 && threadIdx.x < 64) accs[threadIdx.x] = 0.f;   // accs + last-block ticket
  const float* p = (r < 4 * TT) ? (z1 + (size_t)r * CC) : (z2 + (size_t)(r - 4 * TT) * CC);
  unsigned short* o = zb + (size_t)r * CC;
  float4 v = ((const float4*)p)[threadIdx.x];
  float s = v.x * v.x + v.y * v.y + v.z * v.z + v.w * v.w;
  ushort4 u;
  u.x = f2bf(v.x); u.y = f2bf(v.y); u.z = f2bf(v.z); u.w = f2bf(v.w);
  ((ushort4*)o)[threadIdx.x] = u;
#pragma unroll
  for (int off = 32; off > 0; off >>= 1) s += __shfl_down(s, off, 64);
  __shared__ float wred[3];
  int lane = threadIdx.x & 63, w = threadIdx.x >> 6;
  if (lane == 0) wred[w] = s;
  __syncthreads();
  if (threadIdx.x == 0) {
    float tot = wred[0] + wred[1] + wred[2];
    sq[r] = tot; inv[r] = rsqrtf(tot + 1e-12f);
  }
}

// ---------------- shared gram main loop: BK=64, XOR-swizzled LDS ----------------
// NOTE (rounds 4/6/7 post-mortems): (a) LDS must be a direct __shared__ decl in the calling
// __global__, passed at most ONE level (SmemKL& arg — round-5/9-proven); no nested-union refs.
// (b) acc stays acc[4][4] (64 regs) — fat accumulators halve occupancy and break the swizzle
// codegen. (c) NO cooperative/grid.sync structures (~100us/sync on 8-XCD MI355X).
struct SmemKL { unsigned short As[128 * 64]; unsigned short Bs[128 * 64]; };  // 32768 B

__device__ __forceinline__ void gram_mainloop(const unsigned short* __restrict__ A,
                                              const unsigned short* __restrict__ B,
                                              int bm, int bn, SmemKL& st, float4v (&acc)[4][4]) {
  const int lane = threadIdx.x & 63, waveId = threadIdx.x >> 6;
  const int wm = (waveId >> 1) * 64, wn = (waveId & 1) * 64;
  const int lrow = lane & 15, lquad = lane >> 4;
  for (int kk = 0; kk < CC; kk += 64) {
    // stage 128x64 per matrix; LDS slot l holds global chunk (l&7)^(row&7) -> swizzled (conflict-free)
#pragma unroll
    for (int c = 0; c < 4; ++c) {
      int l = c * 256 + threadIdx.x;        // 0..1023 chunks of 8 shorts
      int row = l >> 3, pc = l & 7;
      int sc = pc ^ (row & 7);
      gload_lds16(A + (size_t)(bm + row) * CC + kk + sc * 8, &st.As[l * 8]);
      gload_lds16(B + (size_t)(bn + row) * CC + kk + sc * 8, &st.Bs[l * 8]);
    }
    __syncthreads();
#pragma unroll
    for (int h = 0; h < 2; ++h) {
      short8 af[4], bfr[4];
#pragma unroll
      for (int i = 0; i < 4; ++i) {
        int ra = wm + i * 16 + lrow;
        int ca = (h * 4 + lquad) ^ (ra & 7);
        af[i] = *(const short8*)&st.As[ra * 64 + ca * 8];
        int rb = wn + i * 16 + lrow;
        int cb2 = (h * 4 + lquad) ^ (rb & 7);
        bfr[i] = *(const short8*)&st.Bs[rb * 64 + cb2 * 8];
      }
#pragma unroll
      for (int i = 0; i < 4; ++i)
#pragma unroll
        for (int j = 0; j < 4; ++j)
          acc[i][j] = __builtin_amdgcn_mfma_f32_16x16x32_bf16(af[i], bfr[j], acc[i][j], 0, 0, 0);
    }
    __syncthreads();
  }
}

// ---------------- fused gram: self tiles [0, N_SELF_BLK) then cross tiles ----------------
// Round-1/9-proven monolith + PER-REGION XCD chunking (round-10 post-mortem: whole-grid
// chunking gave 3.3x FETCH cut but piled all heavy-epilogue self tiles onto 2 XCDs ->
// imbalance regression). Per-region: XCD k owns self slice k exactly (3MB zb slice resident
// in its 4MB L2) AND 1.5 contiguous cross pairs (B-slice L2-resident). Identical work mix per
// XCD -> no straggler. Both maps bijective (1088/8, crossN/8 exact). Pure remap, no numerics.
__global__ __launch_bounds__(256, 4) void gram_all(unsigned int crossN,
                                                   const unsigned short* __restrict__ zb,
                                                   unsigned short* __restrict__ gram,
                                                   const float* __restrict__ sqAll,
                                                   const float* __restrict__ invAll, PairTab tab,
                                                   float* __restrict__ prow_v, int* __restrict__ prow_i,
                                                   float* __restrict__ pcol_v, int* __restrict__ pcol_i,
                                                   float* __restrict__ pmin0, float* __restrict__ pmin1) {
  __shared__ union {
    SmemKL st;                        // K-loop staging (32768 B)
    unsigned short tile[128 * TP];    // self epilogue (33792 B)
  } sm;
  __shared__ union {
    struct { float sInvA[128]; float sInvB[128];
             float rowv[2][128]; int rowi[2][128];
             float colv[2][128]; int coli[2][128]; } c;     // cross epilogue (5120 B)
    struct { float sqN[128]; float invN[128]; float sqM[128]; float invM[128]; } s;  // self (2048 B)
  } ep;
  // total LDS 38912 B -> 4 blocks/CU (same as round-1 gram_all)

  int bid;
  {
    int b = (int)blockIdx.x;
    if (b < N_SELF_BLK) {
      bid = (b & 7) * (N_SELF_BLK >> 3) + (b >> 3);             // XCD k <- self slice k
    } else {
      int cb = b - N_SELF_BLK;                                   // (1088%8==0 so cb&7 == b&7)
      bid = N_SELF_BLK + (cb & 7) * ((int)crossN >> 3) + (cb >> 3);
    }
  }
  const bool isSelf = bid < N_SELF_BLK;
  int bm, bn, p = 0, s = 0;
  const unsigned short *A, *B;
  if (isSelf) {
    s = bid / 136;
    int t = bid % 136;
    int ti = 0;
    while (t >= 16 - ti) { t -= 16 - ti; ++ti; }
    int tj = ti + t;           // ti <= tj
    bm = ti * 128; bn = tj * 128;
    A = zb + (size_t)s * TT * CC;
    B = A;
    const float* sqS = sqAll + (size_t)s * TT;
    const float* invS = invAll + (size_t)s * TT;
    if (threadIdx.x < 128) { ep.s.sqN[threadIdx.x] = sqS[bn + threadIdx.x]; ep.s.invN[threadIdx.x] = invS[bn + threadIdx.x]; }
    else { ep.s.sqM[threadIdx.x - 128] = sqS[bm + threadIdx.x - 128]; ep.s.invM[threadIdx.x - 128] = invS[bm + threadIdx.x - 128]; }
  } else {
    int cb = bid - N_SELF_BLK;
    p = cb >> 8;
    int tile = cb & 255;
    bn = (tile & 15) * 128;
    bm = (tile >> 4) * 128;
    A = zb + (size_t)tab.sa[p] * TT * CC;
    B = zb + (size_t)tab.sb[p] * TT * CC;
    if (threadIdx.x < 128) ep.c.sInvA[threadIdx.x] = invAll[(size_t)tab.sa[p] * TT + bm + threadIdx.x];
    else ep.c.sInvB[threadIdx.x - 128] = invAll[(size_t)tab.sb[p] * TT + bn + threadIdx.x - 128];
  }

  float4v acc[4][4];
#pragma unroll
  for (int i = 0; i < 4; ++i)
#pragma unroll
    for (int j = 0; j < 4; ++j) acc[i][j] = (float4v){0.f, 0.f, 0.f, 0.f};

  gram_mainloop(A, B, bm, bn, sm.st, acc);

  const int lane = threadIdx.x & 63, waveId = threadIdx.x >> 6;
  const int wm = (waveId >> 1) * 64, wn = (waveId & 1) * 64;
  const int lrow = lane & 15, lquad = lane >> 4;

  if (isSelf) {
    // ---- scatter acc -> LDS tile as bf16 ----
#pragma unroll
    for (int i = 0; i < 4; ++i)
#pragma unroll
      for (int j = 0; j < 4; ++j)
#pragma unroll
        for (int r = 0; r < 4; ++r) {
          int lr = wm + i * 16 + lquad * 4 + r;
          int lc = wn + j * 16 + lrow;
          sm.tile[lr * TP + lc] = f2bf(acc[i][j][r]);
        }
    __syncthreads();
    unsigned short* G = gram + (size_t)s * TT * TT;
    // ---- direct rows: coalesced 8B stores from LDS ----
    for (int it = 0; it < 16; ++it) {
      int task = it * 256 + threadIdx.x;
      int r = task >> 5;          // 0..127
      int c = task & 31;          // chunk of 4 ushorts
      short4v v = *(const short4v*)&sm.tile[r * TP + c * 4];
      *(short4v*)&G[(size_t)(bm + r) * TT + bn + c * 4] = v;
    }
    // ---- mirror rows (offdiag): transposed LDS reads, coalesced 8B stores ----
    if (bm != bn) {
      for (int it = 0; it < 16; ++it) {
        int task = it * 256 + threadIdx.x;
        int cc = task >> 5;       // mirror row = original col 0..127
        int q = task & 31;        // chunk of 4 original rows
        short4v v;
        v[0] = (short)sm.tile[(q * 4 + 0) * TP + cc];
        v[1] = (short)sm.tile[(q * 4 + 1) * TP + cc];
        v[2] = (short)sm.tile[(q * 4 + 2) * TP + cc];
        v[3] = (short)sm.tile[(q * 4 + 3) * TP + cc];
        *(short4v*)&G[(size_t)(bn + cc) * TT + bm + q * 4] = v;
      }
    }
    // ---- per-slab min partials for top5 threshold (bf16 round-trip values, diag excluded) ----
    if (threadIdx.x < 128) {
      int r = threadIdx.x;
      float m0 = INFINITY, m1 = INFINITY;
      for (int c = 0; c < 128; ++c) {
        if (bm == bn && c == r) continue;
        float g = bf2f(sm.tile[r * TP + c]);
        m0 = fminf(m0, ep.s.sqN[c] - 2.f * g);
        m1 = fminf(m1, -g * ep.s.invN[c]);
      }
      pmin0[((size_t)s * 16 + (bn >> 7)) * TT + bm + r] = m0;
      pmin1[((size_t)s * 16 + (bn >> 7)) * TT + bm + r] = m1;
    } else if (bm != bn) {
      int c = threadIdx.x - 128;
      float m0 = INFINITY, m1 = INFINITY;
      for (int r = 0; r < 128; ++r) {
        float g = bf2f(sm.tile[r * TP + c]);
        m0 = fminf(m0, ep.s.sqM[r] - 2.f * g);
        m1 = fminf(m1, -g * ep.s.invM[r]);
      }
      pmin0[((size_t)s * 16 + (bm >> 7)) * TT + bn + c] = m0;
      pmin1[((size_t)s * 16 + (bm >> 7)) * TT + bn + c] = m1;
    }
    return;
  }

  // ---- cross: fused dual argmin partials ----
  float rbv[4][4]; int rbi[4][4];
#pragma unroll
  for (int i = 0; i < 4; ++i)
#pragma unroll
    for (int r = 0; r < 4; ++r) { rbv[i][r] = INFINITY; rbi[i][r] = TT; }
#pragma unroll
  for (int i = 0; i < 4; ++i)
#pragma unroll
    for (int j = 0; j < 4; ++j) {
      int col = bn + wn + j * 16 + lrow;
      float ivb = ep.c.sInvB[wn + j * 16 + lrow];
#pragma unroll
      for (int r = 0; r < 4; ++r) {
        float v = -acc[i][j][r] * ivb;
        if (v < rbv[i][r]) { rbv[i][r] = v; rbi[i][r] = col; }
      }
    }
#pragma unroll
  for (int m = 1; m <= 8; m <<= 1) {
#pragma unroll
    for (int i = 0; i < 4; ++i)
#pragma unroll
      for (int r = 0; r < 4; ++r) {
        float v2 = __shfl_xor(rbv[i][r], m, 64);
        int i2 = __shfl_xor(rbi[i][r], m, 64);
        if (v2 < rbv[i][r] || (v2 == rbv[i][r] && i2 < rbi[i][r])) { rbv[i][r] = v2; rbi[i][r] = i2; }
      }
  }
  if (lrow == 0) {
#pragma unroll
    for (int i = 0; i < 4; ++i)
#pragma unroll
      for (int r = 0; r < 4; ++r) {
        int lr = wm + i * 16 + lquad * 4 + r;
        ep.c.rowv[wn >> 6][lr] = rbv[i][r]; ep.c.rowi[wn >> 6][lr] = rbi[i][r];
      }
  }

  float cbv[4]; int cbi[4];
#pragma unroll
  for (int j = 0; j < 4; ++j) { cbv[j] = INFINITY; cbi[j] = TT; }
#pragma unroll
  for (int j = 0; j < 4; ++j)
#pragma unroll
    for (int i = 0; i < 4; ++i)
#pragma unroll
      for (int r = 0; r < 4; ++r) {
        int lr = wm + i * 16 + lquad * 4 + r;
        float v = -acc[i][j][r] * ep.c.sInvA[lr];
        if (v < cbv[j]) { cbv[j] = v; cbi[j] = bm + lr; }
      }
#pragma unroll
  for (int m = 16; m <= 32; m <<= 1) {
#pragma unroll
    for (int j = 0; j < 4; ++j) {
      float v2 = __shfl_xor(cbv[j], m, 64);
      int i2 = __shfl_xor(cbi[j], m, 64);
      if (v2 < cbv[j] || (v2 == cbv[j] && i2 < cbi[j])) { cbv[j] = v2; cbi[j] = i2; }
    }
  }
  if (lquad == 0) {
#pragma unroll
    for (int j = 0; j < 4; ++j) {
      int lc = wn + j * 16 + lrow;
      ep.c.colv[wm >> 6][lc] = cbv[j]; ep.c.coli[wm >> 6][lc] = cbi[j];
    }
  }
  __syncthreads();

  int bj = bn >> 7, bi2 = bm >> 7;
  if (threadIdx.x < 128) {
    int t = threadIdx.x;
    float v0 = ep.c.rowv[0][t], v1 = ep.c.rowv[1][t];
    int i0 = ep.c.rowi[0][t], i1 = ep.c.rowi[1][t];
    bool take1 = (v1 < v0) || (v1 == v0 && i1 < i0);
    prow_v[((size_t)p * 16 + bj) * TT + bm + t] = take1 ? v1 : v0;
    prow_i[((size_t)p * 16 + bj) * TT + bm + t] = take1 ? i1 : i0;
  } else {
    int t = threadIdx.x - 128;
    float v0 = ep.c.colv[0][t], v1 = ep.c.colv[1][t];
    int i0 = ep.c.coli[0][t], i1 = ep.c.coli[1][t];
    bool take1 = (v1 < v0) || (v1 == v0 && i1 < i0);
    pcol_v[((size_t)p * 16 + bi2) * TT + bn + t] = take1 ? v1 : v0;
    pcol_i[((size_t)p * 16 + bi2) * TT + bn + t] = take1 ? i1 : i0;
  }
}

// ---------------- fallback: full INS5 scan for one row (exact; correctness guard) ----------------
__device__ void top5_row_full(const unsigned short* __restrict__ G, const float* __restrict__ sq,
                              const float* __restrict__ inv, int i, int lane,
                              int* __restrict__ o0, int* __restrict__ o1) {
  float ak[5]; int ai[5];
  float bk[5]; int bi[5];
#pragma unroll
  for (int t = 0; t < 5; ++t) { ak[t] = INFINITY; ai[t] = TT; bk[t] = INFINITY; bi[t] = TT; }
#pragma unroll
  for (int step = 0; step < 8; ++step) {
    int j4 = (step * 64 + lane) * 4;
    ushort4 g4u = *(const ushort4*)&G[j4];
    float4 s4 = *(const float4*)&sq[j4];
    float4 v4 = *(const float4*)&inv[j4];
#pragma unroll
    for (int c = 0; c < 4; ++c) {
      int j = j4 + c;
      float g = bf2f((c == 0) ? g4u.x : (c == 1) ? g4u.y : (c == 2) ? g4u.z : g4u.w);
      float sv = (c == 0) ? s4.x : (c == 1) ? s4.y : (c == 2) ? s4.z : s4.w;
      float iv = (c == 0) ? v4.x : (c == 1) ? v4.y : (c == 2) ? v4.z : v4.w;
      float k0 = (j == i) ? INFINITY : sv - 2.f * g;
      float k1 = (j == i) ? INFINITY : -g * iv;
      INS5(k0, j, a)
      INS5(k1, j, b)
    }
  }
#pragma unroll
  for (int m = 1; m <= 32; m <<= 1) {
    float ok[5]; int oi[5];
#pragma unroll
    for (int t = 0; t < 5; ++t) { ok[t] = __shfl_xor(ak[t], m, 64); oi[t] = __shfl_xor(ai[t], m, 64); }
#pragma unroll
    for (int t = 0; t < 5; ++t) { INS5(ok[t], oi[t], a) }
#pragma unroll
    for (int t = 0; t < 5; ++t) { ok[t] = __shfl_xor(bk[t], m, 64); oi[t] = __shfl_xor(bi[t], m, 64); }
#pragma unroll
    for (int t = 0; t < 5; ++t) { INS5(ok[t], oi[t], b) }
  }
  if (lane < KK) {
    int v0 = (lane == 0) ? ai[0] : (lane == 1) ? ai[1] : (lane == 2) ? ai[2] : (lane == 3) ? ai[3] : ai[4];
    int v1 = (lane == 0) ? bi[0] : (lane == 1) ? bi[1] : (lane == 2) ? bi[2] : (lane == 3) ? bi[3] : bi[4];
    o0[lane] = v0;
    o1[lane] = v1;
  }
}

// ---------------- single-pass dual top-5: slab-skipping threshold scan ----------------
__device__ void top5_body(int s, int bx, const unsigned short* __restrict__ gram,
                          const float* __restrict__ sqAll, const float* __restrict__ invAll,
                          const float* __restrict__ pmin0, const float* __restrict__ pmin1,
                          int* __restrict__ out0, int* __restrict__ out1) {
  int w = threadIdx.x >> 6, lane = threadIdx.x & 63;
  int i = bx * 4 + w;
  const unsigned short* G = gram + (size_t)s * TT * TT + (size_t)i * TT;
  const float* sq = sqAll + (size_t)s * TT;
  const float* inv = invAll + (size_t)s * TT;

  __shared__ float pvv[4][2][PCAP];
  __shared__ int pix[4][2][PCAP];
  __shared__ int pcnt[4][2];
  if (lane < 2) pcnt[w][lane] = 0;

  // ---- threshold: rank-4 (5th smallest) of 16 slab mins, per mode ----
  int t16 = lane & 15;
  float m0 = pmin0[((size_t)s * 16 + t16) * TT + i];
  float m1 = pmin1[((size_t)s * 16 + t16) * TT + i];
  int r0 = 0, r1 = 0;
#pragma unroll
  for (int d = 1; d < 16; ++d) {
    int h = (t16 + d) & 15;
    int src = (lane & 48) | h;
    float o0 = __shfl(m0, src, 64);
    float o1 = __shfl(m1, src, 64);
    r0 += (o0 < m0 || (o0 == m0 && h < t16)) ? 1 : 0;
    r1 += (o1 < m1 || (o1 == m1 && h < t16)) ? 1 : 0;
  }
  unsigned long long b0 = __ballot(r0 == 4);
  unsigned long long b1 = __ballot(r1 == 4);
  float T0 = __shfl(m0, (int)(__ffsll(b0) - 1), 64);
  float T1 = __shfl(m1, (int)(__ffsll(b1) - 1), 64);

  // slab masks (bits 0..15 of ballots; lanes 16+ are copies)
  unsigned int sl0 = (unsigned int)(__ballot(m0 <= T0) & 0xFFFFull);
  unsigned int sl1 = (unsigned int)(__ballot(m1 <= T1) & 0xFFFFull);
  unsigned int slmask = sl0 | sl1;

  // ---- scan only qualifying slabs (128 cols each, 2 per lane) ----
  while (slmask) {
    int sb = __ffs(slmask) - 1;
    slmask &= slmask - 1;
    int j2 = sb * 128 + lane * 2;
    ushort2 g2 = *(const ushort2*)&G[j2];
    float2 s2 = *(const float2*)&sq[j2];
    float2 v2 = *(const float2*)&inv[j2];
#pragma unroll
    for (int c = 0; c < 2; ++c) {
      int j = j2 + c;
      float g = bf2f((c == 0) ? g2.x : g2.y);
      float sv = (c == 0) ? s2.x : s2.y;
      float iv = (c == 0) ? v2.x : v2.y;
      float k0 = (j == i) ? INFINITY : sv - 2.f * g;
      float k1 = (j == i) ? INFINITY : -g * iv;
      bool c0 = (k0 <= T0), c1 = (k1 <= T1);
      if (__any(c0)) {
        if (c0) {
          int q = atomicAdd(&pcnt[w][0], 1);
          if (q < PCAP) { pvv[w][0][q] = k0; pix[w][0][q] = j; }
        }
      }
      if (__any(c1)) {
        if (c1) {
          int q = atomicAdd(&pcnt[w][1], 1);
          if (q < PCAP) { pvv[w][1][q] = k1; pix[w][1][q] = j; }
        }
      }
    }
  }

  int c0n = pcnt[w][0], c1n = pcnt[w][1];
  if (c0n > PCAP || c1n > PCAP || c0n < KK || c1n < KK) {
    // overflow or (bug-guard) underflow -> exact full scan
    top5_row_full(G, sq, inv, i, lane,
                  out0 + ((size_t)s * TT + i) * KK, out1 + ((size_t)s * TT + i) * KK);
    return;
  }
  // ---- final: exact lexicographic rank of candidates (<= 64, one per lane) ----
  {
    float cv = (lane < c0n) ? pvv[w][0][lane] : INFINITY;
    int ci = (lane < c0n) ? pix[w][0][lane] : TT;
    int r = 0;
    for (int t = 0; t < c0n; ++t) {
      float ov = pvv[w][0][t]; int oi = pix[w][0][t];
      r += lexlt(ov, oi, cv, ci) ? 1 : 0;
    }
    if (lane < c0n && r < KK) out0[((size_t)s * TT + i) * KK + r] = ci;
  }
  {
    float cv = (lane < c1n) ? pvv[w][1][lane] : INFINITY;
    int ci = (lane < c1n) ? pix[w][1][lane] : TT;
    int r = 0;
    for (int t = 0; t < c1n; ++t) {
      float ov = pvv[w][1][t]; int oi = pix[w][1][t];
      r += lexlt(ov, oi, cv, ci) ? 1 : 0;
    }
    if (lane < c1n && r < KK) out1[((size_t)s * TT + i) * KK + r] = ci;
  }
}

// ---------------- argmin stage 2 body (with transpose-dedup remap) ----------------
__device__ void argmin_body(int bx, int p, const float* __restrict__ prow_v, const int* __restrict__ prow_i,
                            const float* __restrict__ pcol_v, const int* __restrict__ pcol_i,
                            const PairMap& pm,
                            int* __restrict__ b_of_a, int* __restrict__ a_of_b) {
  int u = pm.src[p];                   // unique gram pair that was computed
  bool tr = pm.tr[p] != 0;             // this pair's D is the transpose of pair u's D
  int t = bx * 256 + threadIdx.x;
  int isRow = t < TT;
  int x = isRow ? t : t - TT;
  bool useRow = (isRow != 0) != tr;
  const float* pv = (useRow ? prow_v : pcol_v) + (size_t)u * 16 * TT;
  const int* pi = (useRow ? prow_i : pcol_i) + (size_t)u * 16 * TT;
  float best = INFINITY; int bidx = TT;
  for (int s = 0; s < 16; ++s) {
    float v = pv[(size_t)s * TT + x]; int id = pi[(size_t)s * TT + x];
    if (v < best || (v == best && id < bidx)) { best = v; bidx = id; }
  }
  if (isRow) b_of_a[(size_t)p * TT + x] = bidx;
  else       a_of_b[(size_t)p * TT + x] = bidx;
}

// ---------------- fused top5 + argmin stage 2 ----------------
__global__ __launch_bounds__(256) void top5_argmin_fused(const unsigned short* __restrict__ gram,
                                                         const float* __restrict__ sqAll,
                                                         const float* __restrict__ invAll,
                                                         const float* __restrict__ pmin0,
                                                         const float* __restrict__ pmin1,
                                                         int* __restrict__ out0, int* __restrict__ out1,
                                                         const float* __restrict__ prow_v, const int* __restrict__ prow_i,
                                                         const float* __restrict__ pcol_v, const int* __restrict__ pcol_i,
                                                         PairMap pm,
                                                         int* __restrict__ b_of_a, int* __restrict__ a_of_b) {
  unsigned int b = blockIdx.x;
  if (b < 4096) {                                  // top5: was dim3(512, 8)
    top5_body((int)(b >> 9), (int)(b & 511), gram, sqAll, invAll, pmin0, pmin1, out0, out1);
  } else {                                         // argmin: was dim3(16, 12)
    unsigned int t = b - 4096;
    argmin_body((int)(t & 15), (int)(t >> 4), prow_v, prow_i, pcol_v, pcol_i, pm, b_of_a, a_of_b);
  }
}

// ---------------- crossbrain hinge body: 64 rows/block, 1 atomic/block ----------------
__device__ void cb_hinge_body(int bx, int c, const unsigned short* __restrict__ gram, const float* __restrict__ invAll,
                              const int* __restrict__ neigh1, float* __restrict__ cb_acc) {
  int i0 = bx * 64;
  int sa = c, sb = (c < 4) ? (c + 4) : (c - 4);
  const unsigned short* Gs = gram + (size_t)sb * TT * TT;
  const float* invB = invAll + (size_t)sb * TT;
  const int* neighA = neigh1 + (size_t)sa * TT * KK;
  unsigned int seed = 0x13579BDFu + 0x9E3779B9u * (unsigned)c;
  int tid = threadIdx.x;

  __shared__ int targ[64][10];
  __shared__ float sval[64][10];
  for (int t = tid; t < 64 * KK; t += 256) targ[t / KK][t % KK] = neighA[(size_t)i0 * KK + t];
  __syncthreads();
  if (tid < 64) {
    int i = i0 + tid;
    int pos[KK];
#pragma unroll
    for (int k = 0; k < KK; ++k) pos[k] = targ[tid][k];
    unsigned int ctr = 0;
    for (int k = 0; k < KK; ++k) {
      int cand;
      while (true) {
        unsigned int h = mix_hash(seed ^ (unsigned)i, ctr++);
        cand = (int)(h & (TT - 1));
        bool bad = (cand == i);
        for (int t = 0; t < KK; ++t) bad = bad || (cand == pos[t]);
        for (int t = 0; t < k; ++t) bad = bad || (cand == targ[tid][KK + t]);
        if (!bad) break;
      }
      targ[tid][KK + k] = cand;
    }
  }
  __syncthreads();
  for (int t = tid; t < 640; t += 256) {
    int il = t / 10, k = t % 10;
    int tt = targ[il][k];
    sval[il][k] = bf2f(Gs[(size_t)(i0 + il) * TT + tt]) * invB[tt];
  }
  __syncthreads();
  if (tid < 64) {
    int i = i0 + tid;
    float ii = invB[i];
    const float lo = -1.f + 1e-8f, hi = 1.f - 1e-8f;
    float hsum = 0.f;
#pragma unroll
    for (int k = 0; k < KK; ++k) {
      float sp = fminf(fmaxf(sval[tid][k] * ii, lo), hi);
      float sn = fminf(fmaxf(sval[tid][KK + k] * ii, lo), hi);
      float h = sn - sp + 0.05f;
      hsum += (h > 0.f) ? h : 0.f;
    }
#pragma unroll
    for (int off = 32; off > 0; off >>= 1) hsum += __shfl_down(hsum, off, 64);
    if (tid == 0) atomicAdd(&cb_acc[c], hsum);
  }
}

// ---------------- mutual matching body ----------------
__device__ void mutual_body(int p, const int* __restrict__ b_of_a_all,
                            const int* __restrict__ a_of_b_all,
                            int* __restrict__ idxB_all, int* __restrict__ matchedB_all,
                            int* __restrict__ unmatched_all, int* __restrict__ scalars_all) {
  const int* b_of_a = b_of_a_all + (size_t)p * TT;
  const int* a_of_b = a_of_b_all + (size_t)p * TT;
  int* idxB_of_A = idxB_all + (size_t)p * TT;
  int* matchedB = matchedB_all + (size_t)p * TT;
  int* unmatched = unmatched_all + (size_t)p * TT;
  __shared__ int cnt_sh;
  for (int j = threadIdx.x; j < TT; j += 256) matchedB[j] = 0;
  __syncthreads();
  for (int i = threadIdx.x; i < TT; i += 256) {
    int b = b_of_a[i];
    bool mut = (a_of_b[b] == i);
    idxB_of_A[i] = mut ? b : -1;
    if (mut) matchedB[b] = 1;
  }
  __syncthreads();
  if (threadIdx.x == 0) cnt_sh = 0;
  __syncthreads();
  for (int j = threadIdx.x; j < TT; j += 256) {
    if (!matchedB[j]) { int q = atomicAdd(&cnt_sh, 1); unmatched[q] = j; }
  }
  __syncthreads();
  if (threadIdx.x == 0) {
    int c = cnt_sh;
    if (c == 0) { unmatched[0] = 0; c = 1; }
    scalars_all[p * 16] = c;
  }
}

// ---------------- fused cb_hinge + mutual ----------------
__global__ __launch_bounds__(256) void cb_mutual_fused(const unsigned short* __restrict__ gram,
                                                       const float* __restrict__ invAll,
                                                       const int* __restrict__ neigh1, float* __restrict__ cb_acc,
                                                       const int* __restrict__ b_of_a, const int* __restrict__ a_of_b,
                                                       int* __restrict__ idxB_all, int* __restrict__ matchedB_all,
                                                       int* __restrict__ unmatched_all, int* __restrict__ scalars_all) {
  unsigned int b = blockIdx.x;
  if (b < 256) {                                   // cb: was dim3(32, 8)
    cb_hinge_body((int)(b & 31), (int)(b >> 5), gram, invAll, neigh1, cb_acc);
  } else {                                         // mutual: was <<<12>>>
    mutual_body((int)(b - 256), b_of_a, a_of_b, idxB_all, matchedB_all, unmatched_all, scalars_all);
  }
}

// ---------------- NRC hinge + last-block final combine ----------------
// accs layout: [0..7]=cb_acc, [8..31]=nrc_acc (12 pairs x {sum,cnt}), [32]=ticket (uint).
__global__ __launch_bounds__(256) void nrc_hinge_block(const unsigned short* __restrict__ gram, const float* __restrict__ invAll,
                                                       const int* __restrict__ neighC, const int* __restrict__ idxB_all,
                                                       const int* __restrict__ unmatched_all,
                                                       const int* __restrict__ scalars_all,
                                                       PairTab tab, float* __restrict__ accs,
                                                       float* __restrict__ out) {
  int p = blockIdx.y;
  int i0 = blockIdx.x * 64;
  int sa = tab.sa[p], sb = tab.sb[p];
  const unsigned short* Gs = gram + (size_t)sb * TT * TT;
  const float* invB = invAll + (size_t)sb * TT;
  const int* neighA = neighC + (size_t)sa * TT * KK;
  const int* idxB_of_A = idxB_all + (size_t)p * TT;
  const int* unmatched = unmatched_all + (size_t)p * TT;
  unsigned int seed = 0xC0FFEE11u + 0x9E3779B9u * (unsigned)p;
  float* nrc_acc = accs + 8;
  float* acc = nrc_acc + p * 2;
  int tid = threadIdx.x;

  __shared__ int targ[64][10];
  __shared__ float sval[64][10];
  __shared__ unsigned int tmask[64];
  __shared__ int su[64];
  if (tid < 64) { tmask[tid] = 0; su[tid] = idxB_of_A[i0 + tid]; }
  __syncthreads();
  unsigned int neg_count = (unsigned int)scalars_all[p * 16];
  for (int t = tid; t < 64 * KK; t += 256) {
    int il = t / KK, k = t % KK;
    int nb = neighA[(size_t)i0 * KK + t];
    int pb = idxB_of_A[nb];
    targ[il][k] = (pb >= 0) ? pb : 0;
    if (pb >= 0) atomicOr(&tmask[il], 1u << k);
  }
  for (int t = tid; t < 64 * KK; t += 256) {
    int il = t / KK, k = t % KK;
    int i = i0 + il;
    unsigned int r = mix_hash(seed ^ 0xA5A5u, (unsigned)(i * KK + k)) & (TT - 1);
    targ[il][KK + k] = unmatched[r % neg_count];
  }
  __syncthreads();
  for (int t = tid; t < 640; t += 256) {
    int il = t / 10, k = t % 10;
    int u = su[il] >= 0 ? su[il] : 0;
    int tt = targ[il][k];
    sval[il][k] = bf2f(Gs[(size_t)u * TT + tt]) * invB[tt];
  }
  __syncthreads();
  if (tid < 64) {
    int idx = su[tid];
    int u = idx >= 0 ? idx : 0;
    float iu = invB[u];
    unsigned int tm = tmask[tid];
    float hsum = 0.f; int pcnt = 0;
#pragma unroll
    for (int k = 0; k < KK; ++k) {
      if (tm & (1u << k)) {
        float dpos = 1.f - sval[tid][k] * iu;
        float dneg = 1.f - sval[tid][KK + k] * iu;
        float h = dpos - dneg + 0.4f;
        hsum += (h > 0.f) ? h : 0.f;
        pcnt++;
      }
    }
    float hs = 0.f, vc = 0.f;
    if (idx >= 0 && pcnt > 0) { hs = hsum / (float)pcnt; vc = 1.0f; }
#pragma unroll
    for (int off = 32; off > 0; off >>= 1) {
      hs += __shfl_down(hs, off, 64);
      vc += __shfl_down(vc, off, 64);
    }
    if (tid == 0) {
      atomicAdd(&acc[0], hs);
      atomicAdd(&acc[1], vc);
      // last-block ticket: final combine without a separate launch
      __threadfence();
      unsigned int old = atomicAdd((unsigned int*)(accs + 32), 1u);
      if (old == 32u * 12u - 1u) {
        const float* cb_acc = accs;
        float loss2 = 0.f;
        for (int c = 0; c < 8; ++c) loss2 += cb_acc[c] * (1.0f / 10240.0f);
        loss2 *= 0.25f;
        float loss3 = 0.f;
        for (int d = 0; d < 2; ++d) {
          float sx = 0.f;
          for (int t = 0; t < 6; ++t) {
            float cnt = nrc_acc[(d * 6 + t) * 2 + 1];
            float sum = nrc_acc[(d * 6 + t) * 2 + 0];
            sx += (cnt > 0.f) ? (sum / cnt) : 0.f;
          }
          loss3 += sx * (1.f / 6.f);
        }
        out[0] = 10.f * loss2 + 10.f * loss3;
      }
    }
  }
}

// ---------------- host-side numpy RandomState(seed).permutation(12)[:6] ----------------
namespace {
struct MT19937 {
  uint32_t mt[624]; int mti;
  void seed(uint32_t s) {
    mt[0] = s;
    for (int i = 1; i < 624; ++i) mt[i] = 1812433253u * (mt[i - 1] ^ (mt[i - 1] >> 30)) + (uint32_t)i;
    mti = 624;
  }
  uint32_t next() {
    if (mti >= 624) {
      for (int i = 0; i < 624; ++i) {
        uint32_t y = (mt[i] & 0x80000000u) | (mt[(i + 1) % 624] & 0x7fffffffu);
        uint32_t v = y >> 1;
        if (y & 1u) v ^= 0x9908b0dfu;
        mt[i] = mt[(i + 397) % 624] ^ v;
      }
      mti = 0;
    }
    uint32_t y = mt[mti++];
    y ^= y >> 11; y ^= (y << 7) & 0x9d2c5680u; y ^= (y << 15) & 0xefc60000u; y ^= y >> 18;
    return y;
  }
  uint32_t interval(uint32_t mx) {
    uint32_t mask = mx;
    mask |= mask >> 1; mask |= mask >> 2; mask |= mask >> 4; mask |= mask >> 8; mask |= mask >> 16;
    while (true) { uint32_t v = next() & mask; if (v <= mx) return v; }
  }
};
inline void np_perm12_first6(uint32_t seed, int* sel6) {
  int a[12]; for (int i = 0; i < 12; ++i) a[i] = i;
  MT19937 r; r.seed(seed);
  for (int i = 11; i >= 1; --i) { uint32_t j = r.interval((uint32_t)i); int t = a[i]; a[i] = a[j]; a[j] = t; }
  for (int i = 0; i < 6; ++i) sel6[i] = a[i];
}
}  // namespace

extern "C" void kernel_launch(void* const* d_in, const int* in_sizes, int n_in,
                              void* d_out, int out_size, void* d_ws, size_t ws_size,
                              hipStream_t stream) {
  const float* z1 = (const float*)d_in[0];
  const float* z2 = (const float*)d_in[1];
  float* out = (float*)d_out;

  char* base = (char*)d_ws;
  size_t off = 0;
  auto alloc = [&](size_t bytes) -> void* {
    void* p = base + off;
    off = (off + bytes + 255) & ~(size_t)255;
    return p;
  };
  unsigned short* gram   = (unsigned short*)alloc((size_t)8 * TT * TT * 2);  // 67 MB bf16 self grams
  unsigned short* zb     = (unsigned short*)alloc((size_t)8 * TT * CC * 2);
  float* sq              = (float*)alloc((size_t)8 * TT * 4);
  float* inv             = (float*)alloc((size_t)8 * TT * 4);
  int*   neigh1          = (int*)alloc((size_t)8 * TT * KK * 4);
  int*   neighC          = (int*)alloc((size_t)8 * TT * KK * 4);
  float* pmin0           = (float*)alloc((size_t)8 * 16 * TT * 4);   // per-slab row/col mins, mode0
  float* pmin1           = (float*)alloc((size_t)8 * 16 * TT * 4);   // mode1
  float* prow_v          = (float*)alloc((size_t)12 * 16 * TT * 4);
  int*   prow_i          = (int*)alloc((size_t)12 * 16 * TT * 4);
  float* pcol_v          = (float*)alloc((size_t)12 * 16 * TT * 4);
  int*   pcol_i          = (int*)alloc((size_t)12 * 16 * TT * 4);
  int*   b_of_a          = (int*)alloc((size_t)12 * TT * 4);
  int*   a_of_b          = (int*)alloc((size_t)12 * TT * 4);
  int*   idxB            = (int*)alloc((size_t)12 * TT * 4);
  int*   matchedB        = (int*)alloc((size_t)12 * TT * 4);
  int*   unmatched       = (int*)alloc((size_t)12 * TT * 4);
  int*   scalars         = (int*)alloc(12 * 16 * 4);
  float* accs            = (float*)alloc(64 * 4);
  float* cb_acc          = accs;

  // NRC pair selection (numpy RandomState(seed).permutation(12)[:6])
  int sel0[6], sel1[6];
  np_perm12_first6(0u, sel0);
  np_perm12_first6(1u, sel1);
  static const int PP[12] = {0, 0, 0, 1, 1, 1, 2, 2, 2, 3, 3, 3};
  static const int QQ[12] = {1, 2, 3, 0, 2, 3, 0, 1, 3, 0, 1, 2};
  PairTab tab;
  for (int d = 0; d < 2; ++d) {
    const int* sel = (d == 0) ? sel0 : sel1;
    for (int t = 0; t < 6; ++t) {
      int pi_ = PP[sel[t]], qi = QQ[sel[t]];
      int p = d * 6 + t;
      tab.sa[p] = (d == 0) ? pi_ : 4 + pi_;
      tab.sb[p] = (d == 0) ? 4 + qi : qi;
    }
  }

  // transpose-dedup (zero hits for these seeds but harmless)
  PairTab gtab; PairMap pm; int nU = 0;
  for (int p = 0; p < 12; ++p) {
    int f = -1, ftr = 0;
    for (int q = 0; q < nU; ++q) {
      if (gtab.sa[q] == tab.sb[p] && gtab.sb[q] == tab.sa[p]) { f = q; ftr = 1; break; }
      if (gtab.sa[q] == tab.sa[p] && gtab.sb[q] == tab.sb[p]) { f = q; ftr = 0; break; }
    }
    if (f >= 0) { pm.src[p] = f; pm.tr[p] = ftr; }
    else { gtab.sa[nU] = tab.sa[p]; gtab.sb[nU] = tab.sb[p]; pm.src[p] = nU; pm.tr[p] = 0; ++nU; }
  }

  // fused prep (bf16 convert + norms + acc/ticket zeroing)
  prep_kernel<<<8 * TT, 192, 0, stream>>>(z1, z2, zb, sq, inv, accs);

  // fused gram (self then cross), per-region XCD-chunked block swizzle inside the kernel
  unsigned int crossN = (unsigned int)(nU * 256);
  gram_all<<<N_SELF_BLK + crossN, 256, 0, stream>>>(crossN, zb, gram, sq, inv, gtab,
                                                    prow_v, prow_i, pcol_v, pcol_i, pmin0, pmin1);

  // fused top5 (slab-skipping threshold scan) + argmin stage 2
  top5_argmin_fused<<<4096 + 192, 256, 0, stream>>>(gram, sq, inv, pmin0, pmin1, neigh1, neighC,
                                                    prow_v, prow_i, pcol_v, pcol_i, pm, b_of_a, a_of_b);

  // fused cb_hinge + mutual matching
  cb_mutual_fused<<<256 + 12, 256, 0, stream>>>(gram, inv, neigh1, cb_acc,
                                                b_of_a, a_of_b, idxB, matchedB, unmatched, scalars);

  // nrc hinge with folded last-block final combine
  nrc_hinge_block<<<dim3(TT / 64, 12), 256, 0, stream>>>(gram, inv, neighC, idxB, unmatched, scalars,
                                                         tab, accs, out);
}

// Round 12
// 267.587 us; speedup vs baseline: 1.1153x; 1.0524x over previous
//
#include <hip/hip_runtime.h>
#include <cstdint>
#include <cstddef>

#define TT 2048
#define CC 768
#define KK 5
#define PCAP 64   // candidate pool per wave per mode (expected ~8 used)

typedef __attribute__((ext_vector_type(8))) short short8;
typedef __attribute__((ext_vector_type(4))) short short4v;
typedef __attribute__((ext_vector_type(4))) float float4v;

struct PairTab { int sa[12]; int sb[12]; };
struct PairMap { int src[12]; int tr[12]; };

#define N_SELF_BLK (8 * 136)   // 8 slices x 136 upper-triangle 128x128 tiles
#define TP 132                 // padded LDS tile row (ushorts)

// ---------------- device RNG hash ----------------
__device__ __forceinline__ unsigned int mix_hash(unsigned int a, unsigned int b) {
  unsigned long long x = (((unsigned long long)a) << 32) | (unsigned long long)b;
  x ^= x >> 33; x *= 0xff51afd7ed558ccdULL;
  x ^= x >> 33; x *= 0xc4ceb9fe1a85ec53ULL;
  x ^= x >> 33;
  return (unsigned int)(x & 0xffffffffu);
}

__device__ __forceinline__ unsigned short f2bf(float x) {  // RNE fp32->bf16
  union { float f; unsigned int u; } v; v.f = x;
  unsigned int r = v.u + 0x7fffu + ((v.u >> 16) & 1u);
  return (unsigned short)(r >> 16);
}

__device__ __forceinline__ float bf2f(unsigned short u) {
  union { unsigned int i; float f; } v; v.i = ((unsigned int)u) << 16; return v.f;
}

__device__ __forceinline__ void gload_lds16(const void* g, void* l) {
  __builtin_amdgcn_global_load_lds(
      (const __attribute__((address_space(1))) unsigned int*)g,
      (__attribute__((address_space(3))) unsigned int*)l, 16, 0, 0);
}

__device__ __forceinline__ bool lexlt(float k1, int i1, float k2, int i2) {
  return k1 < k2 || (k1 == k2 && i1 < i2);
}

#define INS5(kk_, ii_, L)                                                        \
  if (lexlt(kk_, ii_, L##k[4], L##i[4])) {                                       \
    L##k[4] = kk_; L##i[4] = ii_;                                                \
    if (lexlt(L##k[4], L##i[4], L##k[3], L##i[3])) {                             \
      float tk = L##k[3]; int ti_ = L##i[3]; L##k[3] = L##k[4]; L##i[3] = L##i[4]; L##k[4] = tk; L##i[4] = ti_; \
      if (lexlt(L##k[3], L##i[3], L##k[2], L##i[2])) {                           \
        tk = L##k[2]; ti_ = L##i[2]; L##k[2] = L##k[3]; L##i[2] = L##i[3]; L##k[3] = tk; L##i[3] = ti_; \
        if (lexlt(L##k[2], L##i[2], L##k[1], L##i[1])) {                         \
          tk = L##k[1]; ti_ = L##i[1]; L##k[1] = L##k[2]; L##i[1] = L##i[2]; L##k[2] = tk; L##i[2] = ti_; \
          if (lexlt(L##k[1], L##i[1], L##k[0], L##i[0])) {                       \
            tk = L##k[0]; ti_ = L##i[0]; L##k[0] = L##k[1]; L##i[0] = L##i[1]; L##k[1] = tk; L##i[1] = ti_; \
          }                                                                      \
        }                                                                        \
      }                                                                          \
    }                                                                            \
  }

// ---------------- fused prep: fp32->bf16 + row sumsq/inv-norm + acc/ticket zeroing ----------------
// (summation order preserved exactly; do not restructure — sq/inv feed tie-sensitive argmins)
__global__ __launch_bounds__(192) void prep_kernel(const float* __restrict__ z1, const float* __restrict__ z2,
                                                   unsigned short* __restrict__ zb, float* __restrict__ sq,
                                                   float* __restrict__ inv, float* __restrict__ accs) {
  int r = blockIdx.x;  // 0..16383
  if (r == 0 && threadIdx.x < 64) accs[threadIdx.x] = 0.f;   // accs + last-block ticket
  const float* p = (r < 4 * TT) ? (z1 + (size_t)r * CC) : (z2 + (size_t)(r - 4 * TT) * CC);
  unsigned short* o = zb + (size_t)r * CC;
  float4 v = ((const float4*)p)[threadIdx.x];
  float s = v.x * v.x + v.y * v.y + v.z * v.z + v.w * v.w;
  ushort4 u;
  u.x = f2bf(v.x); u.y = f2bf(v.y); u.z = f2bf(v.z); u.w = f2bf(v.w);
  ((ushort4*)o)[threadIdx.x] = u;
#pragma unroll
  for (int off = 32; off > 0; off >>= 1) s += __shfl_down(s, off, 64);
  __shared__ float wred[3];
  int lane = threadIdx.x & 63, w = threadIdx.x >> 6;
  if (lane == 0) wred[w] = s;
  __syncthreads();
  if (threadIdx.x == 0) {
    float tot = wred[0] + wred[1] + wred[2];
    sq[r] = tot; inv[r] = rsqrtf(tot + 1e-12f);
  }
}

// ---------------- shared gram main loop: BK=64, XOR-swizzled LDS ----------------
// NOTE (rounds 4/6/7 post-mortems): (a) LDS must be a direct __shared__ decl in the calling
// __global__, passed at most ONE level (SmemKL& arg — round-5/9-proven); no nested-union refs.
// (b) acc stays acc[4][4] (64 regs) — fat accumulators halve occupancy and break the swizzle
// codegen. (c) NO cooperative/grid.sync structures (~100us/sync on 8-XCD MI355X).
struct SmemKL { unsigned short As[128 * 64]; unsigned short Bs[128 * 64]; };  // 32768 B

__device__ __forceinline__ void gram_mainloop(const unsigned short* __restrict__ A,
                                              const unsigned short* __restrict__ B,
                                              int bm, int bn, SmemKL& st, float4v (&acc)[4][4]) {
  const int lane = threadIdx.x & 63, waveId = threadIdx.x >> 6;
  const int wm = (waveId >> 1) * 64, wn = (waveId & 1) * 64;
  const int lrow = lane & 15, lquad = lane >> 4;
  for (int kk = 0; kk < CC; kk += 64) {
    // stage 128x64 per matrix; LDS slot l holds global chunk (l&7)^(row&7) -> swizzled (conflict-free)
#pragma unroll
    for (int c = 0; c < 4; ++c) {
      int l = c * 256 + threadIdx.x;        // 0..1023 chunks of 8 shorts
      int row = l >> 3, pc = l & 7;
      int sc = pc ^ (row & 7);
      gload_lds16(A + (size_t)(bm + row) * CC + kk + sc * 8, &st.As[l * 8]);
      gload_lds16(B + (size_t)(bn + row) * CC + kk + sc * 8, &st.Bs[l * 8]);
    }
    __syncthreads();
#pragma unroll
    for (int h = 0; h < 2; ++h) {
      short8 af[4], bfr[4];
#pragma unroll
      for (int i = 0; i < 4; ++i) {
        int ra = wm + i * 16 + lrow;
        int ca = (h * 4 + lquad) ^ (ra & 7);
        af[i] = *(const short8*)&st.As[ra * 64 + ca * 8];
        int rb = wn + i * 16 + lrow;
        int cb2 = (h * 4 + lquad) ^ (rb & 7);
        bfr[i] = *(const short8*)&st.Bs[rb * 64 + cb2 * 8];
      }
#pragma unroll
      for (int i = 0; i < 4; ++i)
#pragma unroll
        for (int j = 0; j < 4; ++j)
          acc[i][j] = __builtin_amdgcn_mfma_f32_16x16x32_bf16(af[i], bfr[j], acc[i][j], 0, 0, 0);
    }
    __syncthreads();
  }
}

// ---------------- fused gram: self tiles [0, N_SELF_BLK) then cross tiles ----------------
// Round-1/9-proven monolith + per-region XCD chunking (round-11-verified: FETCH 259->71MB,
// gram_all 151.9->142.2us, no imbalance). Pure remap, no numerics.
__global__ __launch_bounds__(256, 4) void gram_all(unsigned int crossN,
                                                   const unsigned short* __restrict__ zb,
                                                   unsigned short* __restrict__ gram,
                                                   const float* __restrict__ sqAll,
                                                   const float* __restrict__ invAll, PairTab tab,
                                                   float* __restrict__ prow_v, int* __restrict__ prow_i,
                                                   float* __restrict__ pcol_v, int* __restrict__ pcol_i,
                                                   float* __restrict__ pmin0, float* __restrict__ pmin1) {
  __shared__ union {
    SmemKL st;                        // K-loop staging (32768 B)
    unsigned short tile[128 * TP];    // self epilogue (33792 B)
  } sm;
  __shared__ union {
    struct { float sInvA[128]; float sInvB[128];
             float rowv[2][128]; int rowi[2][128];
             float colv[2][128]; int coli[2][128]; } c;     // cross epilogue (5120 B)
    struct { float sqN[128]; float invN[128]; float sqM[128]; float invM[128]; } s;  // self (2048 B)
  } ep;
  // total LDS 38912 B -> 4 blocks/CU

  int bid;
  {
    int b = (int)blockIdx.x;
    if (b < N_SELF_BLK) {
      bid = (b & 7) * (N_SELF_BLK >> 3) + (b >> 3);             // XCD k <- self slice k
    } else {
      int cb = b - N_SELF_BLK;                                   // (1088%8==0 so cb&7 == b&7)
      bid = N_SELF_BLK + (cb & 7) * ((int)crossN >> 3) + (cb >> 3);
    }
  }
  const bool isSelf = bid < N_SELF_BLK;
  int bm, bn, p = 0, s = 0;
  const unsigned short *A, *B;
  if (isSelf) {
    s = bid / 136;
    int t = bid % 136;
    int ti = 0;
    while (t >= 16 - ti) { t -= 16 - ti; ++ti; }
    int tj = ti + t;           // ti <= tj
    bm = ti * 128; bn = tj * 128;
    A = zb + (size_t)s * TT * CC;
    B = A;
    const float* sqS = sqAll + (size_t)s * TT;
    const float* invS = invAll + (size_t)s * TT;
    if (threadIdx.x < 128) { ep.s.sqN[threadIdx.x] = sqS[bn + threadIdx.x]; ep.s.invN[threadIdx.x] = invS[bn + threadIdx.x]; }
    else { ep.s.sqM[threadIdx.x - 128] = sqS[bm + threadIdx.x - 128]; ep.s.invM[threadIdx.x - 128] = invS[bm + threadIdx.x - 128]; }
  } else {
    int cb = bid - N_SELF_BLK;
    p = cb >> 8;
    int tile = cb & 255;
    bn = (tile & 15) * 128;
    bm = (tile >> 4) * 128;
    A = zb + (size_t)tab.sa[p] * TT * CC;
    B = zb + (size_t)tab.sb[p] * TT * CC;
    if (threadIdx.x < 128) ep.c.sInvA[threadIdx.x] = invAll[(size_t)tab.sa[p] * TT + bm + threadIdx.x];
    else ep.c.sInvB[threadIdx.x - 128] = invAll[(size_t)tab.sb[p] * TT + bn + threadIdx.x - 128];
  }

  float4v acc[4][4];
#pragma unroll
  for (int i = 0; i < 4; ++i)
#pragma unroll
    for (int j = 0; j < 4; ++j) acc[i][j] = (float4v){0.f, 0.f, 0.f, 0.f};

  gram_mainloop(A, B, bm, bn, sm.st, acc);

  const int lane = threadIdx.x & 63, waveId = threadIdx.x >> 6;
  const int wm = (waveId >> 1) * 64, wn = (waveId & 1) * 64;
  const int lrow = lane & 15, lquad = lane >> 4;

  if (isSelf) {
    // ---- scatter acc -> LDS tile as bf16 ----
#pragma unroll
    for (int i = 0; i < 4; ++i)
#pragma unroll
      for (int j = 0; j < 4; ++j)
#pragma unroll
        for (int r = 0; r < 4; ++r) {
          int lr = wm + i * 16 + lquad * 4 + r;
          int lc = wn + j * 16 + lrow;
          sm.tile[lr * TP + lc] = f2bf(acc[i][j][r]);
        }
    __syncthreads();
    unsigned short* G = gram + (size_t)s * TT * TT;
    // ---- direct rows: coalesced 8B stores from LDS ----
    for (int it = 0; it < 16; ++it) {
      int task = it * 256 + threadIdx.x;
      int r = task >> 5;          // 0..127
      int c = task & 31;          // chunk of 4 ushorts
      short4v v = *(const short4v*)&sm.tile[r * TP + c * 4];
      *(short4v*)&G[(size_t)(bm + r) * TT + bn + c * 4] = v;
    }
    // ---- mirror rows (offdiag): transposed LDS reads, coalesced 8B stores ----
    if (bm != bn) {
      for (int it = 0; it < 16; ++it) {
        int task = it * 256 + threadIdx.x;
        int cc = task >> 5;       // mirror row = original col 0..127
        int q = task & 31;        // chunk of 4 original rows
        short4v v;
        v[0] = (short)sm.tile[(q * 4 + 0) * TP + cc];
        v[1] = (short)sm.tile[(q * 4 + 1) * TP + cc];
        v[2] = (short)sm.tile[(q * 4 + 2) * TP + cc];
        v[3] = (short)sm.tile[(q * 4 + 3) * TP + cc];
        *(short4v*)&G[(size_t)(bn + cc) * TT + bm + q * 4] = v;
      }
    }
    // ---- per-slab min partials for top5 threshold (bf16 round-trip values, diag excluded) ----
    if (threadIdx.x < 128) {
      int r = threadIdx.x;
      float m0 = INFINITY, m1 = INFINITY;
      for (int c = 0; c < 128; ++c) {
        if (bm == bn && c == r) continue;
        float g = bf2f(sm.tile[r * TP + c]);
        m0 = fminf(m0, ep.s.sqN[c] - 2.f * g);
        m1 = fminf(m1, -g * ep.s.invN[c]);
      }
      pmin0[((size_t)s * 16 + (bn >> 7)) * TT + bm + r] = m0;
      pmin1[((size_t)s * 16 + (bn >> 7)) * TT + bm + r] = m1;
    } else if (bm != bn) {
      int c = threadIdx.x - 128;
      float m0 = INFINITY, m1 = INFINITY;
      for (int r = 0; r < 128; ++r) {
        float g = bf2f(sm.tile[r * TP + c]);
        m0 = fminf(m0, ep.s.sqM[r] - 2.f * g);
        m1 = fminf(m1, -g * ep.s.invM[r]);
      }
      pmin0[((size_t)s * 16 + (bm >> 7)) * TT + bn + c] = m0;
      pmin1[((size_t)s * 16 + (bm >> 7)) * TT + bn + c] = m1;
    }
    return;
  }

  // ---- cross: fused dual argmin partials ----
  float rbv[4][4]; int rbi[4][4];
#pragma unroll
  for (int i = 0; i < 4; ++i)
#pragma unroll
    for (int r = 0; r < 4; ++r) { rbv[i][r] = INFINITY; rbi[i][r] = TT; }
#pragma unroll
  for (int i = 0; i < 4; ++i)
#pragma unroll
    for (int j = 0; j < 4; ++j) {
      int col = bn + wn + j * 16 + lrow;
      float ivb = ep.c.sInvB[wn + j * 16 + lrow];
#pragma unroll
      for (int r = 0; r < 4; ++r) {
        float v = -acc[i][j][r] * ivb;
        if (v < rbv[i][r]) { rbv[i][r] = v; rbi[i][r] = col; }
      }
    }
#pragma unroll
  for (int m = 1; m <= 8; m <<= 1) {
#pragma unroll
    for (int i = 0; i < 4; ++i)
#pragma unroll
      for (int r = 0; r < 4; ++r) {
        float v2 = __shfl_xor(rbv[i][r], m, 64);
        int i2 = __shfl_xor(rbi[i][r], m, 64);
        if (v2 < rbv[i][r] || (v2 == rbv[i][r] && i2 < rbi[i][r])) { rbv[i][r] = v2; rbi[i][r] = i2; }
      }
  }
  if (lrow == 0) {
#pragma unroll
    for (int i = 0; i < 4; ++i)
#pragma unroll
      for (int r = 0; r < 4; ++r) {
        int lr = wm + i * 16 + lquad * 4 + r;
        ep.c.rowv[wn >> 6][lr] = rbv[i][r]; ep.c.rowi[wn >> 6][lr] = rbi[i][r];
      }
  }

  float cbv[4]; int cbi[4];
#pragma unroll
  for (int j = 0; j < 4; ++j) { cbv[j] = INFINITY; cbi[j] = TT; }
#pragma unroll
  for (int j = 0; j < 4; ++j)
#pragma unroll
    for (int i = 0; i < 4; ++i)
#pragma unroll
      for (int r = 0; r < 4; ++r) {
        int lr = wm + i * 16 + lquad * 4 + r;
        float v = -acc[i][j][r] * ep.c.sInvA[lr];
        if (v < cbv[j]) { cbv[j] = v; cbi[j] = bm + lr; }
      }
#pragma unroll
  for (int m = 16; m <= 32; m <<= 1) {
#pragma unroll
    for (int j = 0; j < 4; ++j) {
      float v2 = __shfl_xor(cbv[j], m, 64);
      int i2 = __shfl_xor(cbi[j], m, 64);
      if (v2 < cbv[j] || (v2 == cbv[j] && i2 < cbi[j])) { cbv[j] = v2; cbi[j] = i2; }
    }
  }
  if (lquad == 0) {
#pragma unroll
    for (int j = 0; j < 4; ++j) {
      int lc = wn + j * 16 + lrow;
      ep.c.colv[wm >> 6][lc] = cbv[j]; ep.c.coli[wm >> 6][lc] = cbi[j];
    }
  }
  __syncthreads();

  int bj = bn >> 7, bi2 = bm >> 7;
  if (threadIdx.x < 128) {
    int t = threadIdx.x;
    float v0 = ep.c.rowv[0][t], v1 = ep.c.rowv[1][t];
    int i0 = ep.c.rowi[0][t], i1 = ep.c.rowi[1][t];
    bool take1 = (v1 < v0) || (v1 == v0 && i1 < i0);
    prow_v[((size_t)p * 16 + bj) * TT + bm + t] = take1 ? v1 : v0;
    prow_i[((size_t)p * 16 + bj) * TT + bm + t] = take1 ? i1 : i0;
  } else {
    int t = threadIdx.x - 128;
    float v0 = ep.c.colv[0][t], v1 = ep.c.colv[1][t];
    int i0 = ep.c.coli[0][t], i1 = ep.c.coli[1][t];
    bool take1 = (v1 < v0) || (v1 == v0 && i1 < i0);
    pcol_v[((size_t)p * 16 + bi2) * TT + bn + t] = take1 ? v1 : v0;
    pcol_i[((size_t)p * 16 + bi2) * TT + bn + t] = take1 ? i1 : i0;
  }
}

// ---------------- fallback: full INS5 scan for one row (exact; correctness guard) ----------------
__device__ void top5_row_full(const unsigned short* __restrict__ G, const float* __restrict__ sq,
                              const float* __restrict__ inv, int i, int lane,
                              int* __restrict__ o0, int* __restrict__ o1) {
  float ak[5]; int ai[5];
  float bk[5]; int bi[5];
#pragma unroll
  for (int t = 0; t < 5; ++t) { ak[t] = INFINITY; ai[t] = TT; bk[t] = INFINITY; bi[t] = TT; }
#pragma unroll
  for (int step = 0; step < 8; ++step) {
    int j4 = (step * 64 + lane) * 4;
    ushort4 g4u = *(const ushort4*)&G[j4];
    float4 s4 = *(const float4*)&sq[j4];
    float4 v4 = *(const float4*)&inv[j4];
#pragma unroll
    for (int c = 0; c < 4; ++c) {
      int j = j4 + c;
      float g = bf2f((c == 0) ? g4u.x : (c == 1) ? g4u.y : (c == 2) ? g4u.z : g4u.w);
      float sv = (c == 0) ? s4.x : (c == 1) ? s4.y : (c == 2) ? s4.z : s4.w;
      float iv = (c == 0) ? v4.x : (c == 1) ? v4.y : (c == 2) ? v4.z : v4.w;
      float k0 = (j == i) ? INFINITY : sv - 2.f * g;
      float k1 = (j == i) ? INFINITY : -g * iv;
      INS5(k0, j, a)
      INS5(k1, j, b)
    }
  }
#pragma unroll
  for (int m = 1; m <= 32; m <<= 1) {
    float ok[5]; int oi[5];
#pragma unroll
    for (int t = 0; t < 5; ++t) { ok[t] = __shfl_xor(ak[t], m, 64); oi[t] = __shfl_xor(ai[t], m, 64); }
#pragma unroll
    for (int t = 0; t < 5; ++t) { INS5(ok[t], oi[t], a) }
#pragma unroll
    for (int t = 0; t < 5; ++t) { ok[t] = __shfl_xor(bk[t], m, 64); oi[t] = __shfl_xor(bi[t], m, 64); }
#pragma unroll
    for (int t = 0; t < 5; ++t) { INS5(ok[t], oi[t], b) }
  }
  if (lane < KK) {
    int v0 = (lane == 0) ? ai[0] : (lane == 1) ? ai[1] : (lane == 2) ? ai[2] : (lane == 3) ? ai[3] : ai[4];
    int v1 = (lane == 0) ? bi[0] : (lane == 1) ? bi[1] : (lane == 2) ? bi[2] : (lane == 3) ? bi[3] : bi[4];
    o0[lane] = v0;
    o1[lane] = v1;
  }
}

// ---------------- single-pass dual top-5: slab-skipping threshold scan ----------------
__device__ void top5_body(int s, int bx, const unsigned short* __restrict__ gram,
                          const float* __restrict__ sqAll, const float* __restrict__ invAll,
                          const float* __restrict__ pmin0, const float* __restrict__ pmin1,
                          int* __restrict__ out0, int* __restrict__ out1) {
  int w = threadIdx.x >> 6, lane = threadIdx.x & 63;
  int i = bx * 4 + w;
  const unsigned short* G = gram + (size_t)s * TT * TT + (size_t)i * TT;
  const float* sq = sqAll + (size_t)s * TT;
  const float* inv = invAll + (size_t)s * TT;

  __shared__ float pvv[4][2][PCAP];
  __shared__ int pix[4][2][PCAP];
  __shared__ int pcnt[4][2];
  if (lane < 2) pcnt[w][lane] = 0;

  // ---- threshold: rank-4 (5th smallest) of 16 slab mins, per mode ----
  int t16 = lane & 15;
  float m0 = pmin0[((size_t)s * 16 + t16) * TT + i];
  float m1 = pmin1[((size_t)s * 16 + t16) * TT + i];
  int r0 = 0, r1 = 0;
#pragma unroll
  for (int d = 1; d < 16; ++d) {
    int h = (t16 + d) & 15;
    int src = (lane & 48) | h;
    float o0 = __shfl(m0, src, 64);
    float o1 = __shfl(m1, src, 64);
    r0 += (o0 < m0 || (o0 == m0 && h < t16)) ? 1 : 0;
    r1 += (o1 < m1 || (o1 == m1 && h < t16)) ? 1 : 0;
  }
  unsigned long long b0 = __ballot(r0 == 4);
  unsigned long long b1 = __ballot(r1 == 4);
  float T0 = __shfl(m0, (int)(__ffsll(b0) - 1), 64);
  float T1 = __shfl(m1, (int)(__ffsll(b1) - 1), 64);

  // slab masks (bits 0..15 of ballots; lanes 16+ are copies)
  unsigned int sl0 = (unsigned int)(__ballot(m0 <= T0) & 0xFFFFull);
  unsigned int sl1 = (unsigned int)(__ballot(m1 <= T1) & 0xFFFFull);
  unsigned int slmask = sl0 | sl1;

  // ---- scan only qualifying slabs (128 cols each, 2 per lane) ----
  while (slmask) {
    int sb = __ffs(slmask) - 1;
    slmask &= slmask - 1;
    int j2 = sb * 128 + lane * 2;
    ushort2 g2 = *(const ushort2*)&G[j2];
    float2 s2 = *(const float2*)&sq[j2];
    float2 v2 = *(const float2*)&inv[j2];
#pragma unroll
    for (int c = 0; c < 2; ++c) {
      int j = j2 + c;
      float g = bf2f((c == 0) ? g2.x : g2.y);
      float sv = (c == 0) ? s2.x : s2.y;
      float iv = (c == 0) ? v2.x : v2.y;
      float k0 = (j == i) ? INFINITY : sv - 2.f * g;
      float k1 = (j == i) ? INFINITY : -g * iv;
      bool c0 = (k0 <= T0), c1 = (k1 <= T1);
      if (__any(c0)) {
        if (c0) {
          int q = atomicAdd(&pcnt[w][0], 1);
          if (q < PCAP) { pvv[w][0][q] = k0; pix[w][0][q] = j; }
        }
      }
      if (__any(c1)) {
        if (c1) {
          int q = atomicAdd(&pcnt[w][1], 1);
          if (q < PCAP) { pvv[w][1][q] = k1; pix[w][1][q] = j; }
        }
      }
    }
  }

  int c0n = pcnt[w][0], c1n = pcnt[w][1];
  if (c0n > PCAP || c1n > PCAP || c0n < KK || c1n < KK) {
    // overflow or (bug-guard) underflow -> exact full scan
    top5_row_full(G, sq, inv, i, lane,
                  out0 + ((size_t)s * TT + i) * KK, out1 + ((size_t)s * TT + i) * KK);
    return;
  }
  // ---- final: exact lexicographic rank of candidates (<= 64, one per lane) ----
  {
    float cv = (lane < c0n) ? pvv[w][0][lane] : INFINITY;
    int ci = (lane < c0n) ? pix[w][0][lane] : TT;
    int r = 0;
    for (int t = 0; t < c0n; ++t) {
      float ov = pvv[w][0][t]; int oi = pix[w][0][t];
      r += lexlt(ov, oi, cv, ci) ? 1 : 0;
    }
    if (lane < c0n && r < KK) out0[((size_t)s * TT + i) * KK + r] = ci;
  }
  {
    float cv = (lane < c1n) ? pvv[w][1][lane] : INFINITY;
    int ci = (lane < c1n) ? pix[w][1][lane] : TT;
    int r = 0;
    for (int t = 0; t < c1n; ++t) {
      float ov = pvv[w][1][t]; int oi = pix[w][1][t];
      r += lexlt(ov, oi, cv, ci) ? 1 : 0;
    }
    if (lane < c1n && r < KK) out1[((size_t)s * TT + i) * KK + r] = ci;
  }
}

// ---------------- argmin stage 2 body (with transpose-dedup remap) ----------------
__device__ void argmin_body(int bx, int p, const float* __restrict__ prow_v, const int* __restrict__ prow_i,
                            const float* __restrict__ pcol_v, const int* __restrict__ pcol_i,
                            const PairMap& pm,
                            int* __restrict__ b_of_a, int* __restrict__ a_of_b) {
  int u = pm.src[p];                   // unique gram pair that was computed
  bool tr = pm.tr[p] != 0;             // this pair's D is the transpose of pair u's D
  int t = bx * 256 + threadIdx.x;
  int isRow = t < TT;
  int x = isRow ? t : t - TT;
  bool useRow = (isRow != 0) != tr;
  const float* pv = (useRow ? prow_v : pcol_v) + (size_t)u * 16 * TT;
  const int* pi = (useRow ? prow_i : pcol_i) + (size_t)u * 16 * TT;
  float best = INFINITY; int bidx = TT;
  for (int s = 0; s < 16; ++s) {
    float v = pv[(size_t)s * TT + x]; int id = pi[(size_t)s * TT + x];
    if (v < best || (v == best && id < bidx)) { best = v; bidx = id; }
  }
  if (isRow) b_of_a[(size_t)p * TT + x] = bidx;
  else       a_of_b[(size_t)p * TT + x] = bidx;
}

// ---------------- fused top5 + argmin stage 2 ----------------
__global__ __launch_bounds__(256) void top5_argmin_fused(const unsigned short* __restrict__ gram,
                                                         const float* __restrict__ sqAll,
                                                         const float* __restrict__ invAll,
                                                         const float* __restrict__ pmin0,
                                                         const float* __restrict__ pmin1,
                                                         int* __restrict__ out0, int* __restrict__ out1,
                                                         const float* __restrict__ prow_v, const int* __restrict__ prow_i,
                                                         const float* __restrict__ pcol_v, const int* __restrict__ pcol_i,
                                                         PairMap pm,
                                                         int* __restrict__ b_of_a, int* __restrict__ a_of_b) {
  unsigned int b = blockIdx.x;
  if (b < 4096) {                                  // top5: was dim3(512, 8)
    top5_body((int)(b >> 9), (int)(b & 511), gram, sqAll, invAll, pmin0, pmin1, out0, out1);
  } else {                                         // argmin: was dim3(16, 12)
    unsigned int t = b - 4096;
    argmin_body((int)(t & 15), (int)(t >> 4), prow_v, prow_i, pcol_v, pcol_i, pm, b_of_a, a_of_b);
  }
}

// ---------------- crossbrain hinge body: 64 rows/block, 1 atomic/block ----------------
__device__ void cb_hinge_body(int bx, int c, const unsigned short* __restrict__ gram, const float* __restrict__ invAll,
                              const int* __restrict__ neigh1, float* __restrict__ cb_acc) {
  int i0 = bx * 64;
  int sa = c, sb = (c < 4) ? (c + 4) : (c - 4);
  const unsigned short* Gs = gram + (size_t)sb * TT * TT;
  const float* invB = invAll + (size_t)sb * TT;
  const int* neighA = neigh1 + (size_t)sa * TT * KK;
  unsigned int seed = 0x13579BDFu + 0x9E3779B9u * (unsigned)c;
  int tid = threadIdx.x;

  __shared__ int targ[64][10];
  __shared__ float sval[64][10];
  for (int t = tid; t < 64 * KK; t += 256) targ[t / KK][t % KK] = neighA[(size_t)i0 * KK + t];
  __syncthreads();
  if (tid < 64) {
    int i = i0 + tid;
    int pos[KK];
#pragma unroll
    for (int k = 0; k < KK; ++k) pos[k] = targ[tid][k];
    unsigned int ctr = 0;
    for (int k = 0; k < KK; ++k) {
      int cand;
      while (true) {
        unsigned int h = mix_hash(seed ^ (unsigned)i, ctr++);
        cand = (int)(h & (TT - 1));
        bool bad = (cand == i);
        for (int t = 0; t < KK; ++t) bad = bad || (cand == pos[t]);
        for (int t = 0; t < k; ++t) bad = bad || (cand == targ[tid][KK + t]);
        if (!bad) break;
      }
      targ[tid][KK + k] = cand;
    }
  }
  __syncthreads();
  for (int t = tid; t < 640; t += 256) {
    int il = t / 10, k = t % 10;
    int tt = targ[il][k];
    sval[il][k] = bf2f(Gs[(size_t)(i0 + il) * TT + tt]) * invB[tt];
  }
  __syncthreads();
  if (tid < 64) {
    int i = i0 + tid;
    float ii = invB[i];
    const float lo = -1.f + 1e-8f, hi = 1.f - 1e-8f;
    float hsum = 0.f;
#pragma unroll
    for (int k = 0; k < KK; ++k) {
      float sp = fminf(fmaxf(sval[tid][k] * ii, lo), hi);
      float sn = fminf(fmaxf(sval[tid][KK + k] * ii, lo), hi);
      float h = sn - sp + 0.05f;
      hsum += (h > 0.f) ? h : 0.f;
    }
#pragma unroll
    for (int off = 32; off > 0; off >>= 1) hsum += __shfl_down(hsum, off, 64);
    if (tid == 0) atomicAdd(&cb_acc[c], hsum);
  }
}

// ---------------- mutual matching (standalone tiny launch; depends only on argmin) ----------------
__global__ __launch_bounds__(256) void mutual_only(const int* __restrict__ b_of_a_all,
                                                   const int* __restrict__ a_of_b_all,
                                                   int* __restrict__ idxB_all, int* __restrict__ matchedB_all,
                                                   int* __restrict__ unmatched_all, int* __restrict__ scalars_all) {
  int p = blockIdx.x;
  const int* b_of_a = b_of_a_all + (size_t)p * TT;
  const int* a_of_b = a_of_b_all + (size_t)p * TT;
  int* idxB_of_A = idxB_all + (size_t)p * TT;
  int* matchedB = matchedB_all + (size_t)p * TT;
  int* unmatched = unmatched_all + (size_t)p * TT;
  __shared__ int cnt_sh;
  for (int j = threadIdx.x; j < TT; j += 256) matchedB[j] = 0;
  __syncthreads();
  for (int i = threadIdx.x; i < TT; i += 256) {
    int b = b_of_a[i];
    bool mut = (a_of_b[b] == i);
    idxB_of_A[i] = mut ? b : -1;
    if (mut) matchedB[b] = 1;
  }
  __syncthreads();
  if (threadIdx.x == 0) cnt_sh = 0;
  __syncthreads();
  for (int j = threadIdx.x; j < TT; j += 256) {
    if (!matchedB[j]) { int q = atomicAdd(&cnt_sh, 1); unmatched[q] = j; }
  }
  __syncthreads();
  if (threadIdx.x == 0) {
    int c = cnt_sh;
    if (c == 0) { unmatched[0] = 0; c = 1; }
    scalars_all[p * 16] = c;
  }
}

// ---------------- NRC hinge body: 64 rows/block, 2 atomics/block ----------------
__device__ void nrc_body(int bx, int p, const unsigned short* __restrict__ gram, const float* __restrict__ invAll,
                         const int* __restrict__ neighC, const int* __restrict__ idxB_all,
                         const int* __restrict__ unmatched_all, const int* __restrict__ scalars_all,
                         const PairTab& tab, float* __restrict__ nrc_acc) {
  int i0 = bx * 64;
  int sa = tab.sa[p], sb = tab.sb[p];
  const unsigned short* Gs = gram + (size_t)sb * TT * TT;
  const float* invB = invAll + (size_t)sb * TT;
  const int* neighA = neighC + (size_t)sa * TT * KK;
  const int* idxB_of_A = idxB_all + (size_t)p * TT;
  const int* unmatched = unmatched_all + (size_t)p * TT;
  unsigned int seed = 0xC0FFEE11u + 0x9E3779B9u * (unsigned)p;
  float* acc = nrc_acc + p * 2;
  int tid = threadIdx.x;

  __shared__ int targ[64][10];
  __shared__ float sval[64][10];
  __shared__ unsigned int tmask[64];
  __shared__ int su[64];
  if (tid < 64) { tmask[tid] = 0; su[tid] = idxB_of_A[i0 + tid]; }
  __syncthreads();
  unsigned int neg_count = (unsigned int)scalars_all[p * 16];
  for (int t = tid; t < 64 * KK; t += 256) {
    int il = t / KK, k = t % KK;
    int nb = neighA[(size_t)i0 * KK + t];
    int pb = idxB_of_A[nb];
    targ[il][k] = (pb >= 0) ? pb : 0;
    if (pb >= 0) atomicOr(&tmask[il], 1u << k);
  }
  for (int t = tid; t < 64 * KK; t += 256) {
    int il = t / KK, k = t % KK;
    int i = i0 + il;
    unsigned int r = mix_hash(seed ^ 0xA5A5u, (unsigned)(i * KK + k)) & (TT - 1);
    targ[il][KK + k] = unmatched[r % neg_count];
  }
  __syncthreads();
  for (int t = tid; t < 640; t += 256) {
    int il = t / 10, k = t % 10;
    int u = su[il] >= 0 ? su[il] : 0;
    int tt = targ[il][k];
    sval[il][k] = bf2f(Gs[(size_t)u * TT + tt]) * invB[tt];
  }
  __syncthreads();
  if (tid < 64) {
    int idx = su[tid];
    int u = idx >= 0 ? idx : 0;
    float iu = invB[u];
    unsigned int tm = tmask[tid];
    float hsum = 0.f; int pcnt = 0;
#pragma unroll
    for (int k = 0; k < KK; ++k) {
      if (tm & (1u << k)) {
        float dpos = 1.f - sval[tid][k] * iu;
        float dneg = 1.f - sval[tid][KK + k] * iu;
        float h = dpos - dneg + 0.4f;
        hsum += (h > 0.f) ? h : 0.f;
        pcnt++;
      }
    }
    float hs = 0.f, vc = 0.f;
    if (idx >= 0 && pcnt > 0) { hs = hsum / (float)pcnt; vc = 1.0f; }
#pragma unroll
    for (int off = 32; off > 0; off >>= 1) {
      hs += __shfl_down(hs, off, 64);
      vc += __shfl_down(vc, off, 64);
    }
    if (tid == 0) {
      atomicAdd(&acc[0], hs);
      atomicAdd(&acc[1], vc);
    }
  }
}

// ---------------- fused cb_hinge + NRC + last-block final combine ----------------
// cb needs only neigh1 (ready); nrc needs mutual (ready). 640 blocks co-resident -> duration
// ~= max(cb, nrc) not sum. accs: [0..7]=cb, [8..31]=nrc {sum,cnt}x12, [32]=ticket (all 640 blocks).
__global__ __launch_bounds__(256) void cb_nrc_fused(const unsigned short* __restrict__ gram,
                                                    const float* __restrict__ invAll,
                                                    const int* __restrict__ neigh1,
                                                    const int* __restrict__ neighC,
                                                    const int* __restrict__ idxB_all,
                                                    const int* __restrict__ unmatched_all,
                                                    const int* __restrict__ scalars_all,
                                                    PairTab tab, float* __restrict__ accs,
                                                    float* __restrict__ out) {
  unsigned int b = blockIdx.x;
  if (b < 256u) {
    cb_hinge_body((int)(b & 31), (int)(b >> 5), gram, invAll, neigh1, accs /*cb_acc*/);
  } else {
    unsigned int u = b - 256u;                      // 0..383: nrc, was dim3(32, 12)
    nrc_body((int)(u & 31), (int)(u >> 5), gram, invAll, neighC, idxB_all, unmatched_all,
             scalars_all, tab, accs + 8 /*nrc_acc*/);
  }
  if (threadIdx.x == 0) {
    __threadfence();
    unsigned int old = atomicAdd((unsigned int*)(accs + 32), 1u);
    if (old == 640u - 1u) {
      __threadfence();
      const float* cb_acc = accs;
      const float* nrc_acc = accs + 8;
      float loss2 = 0.f;
      for (int c = 0; c < 8; ++c) loss2 += cb_acc[c] * (1.0f / 10240.0f);
      loss2 *= 0.25f;
      float loss3 = 0.f;
      for (int d = 0; d < 2; ++d) {
        float sx = 0.f;
        for (int t = 0; t < 6; ++t) {
          float cnt = nrc_acc[(d * 6 + t) * 2 + 1];
          float sum = nrc_acc[(d * 6 + t) * 2 + 0];
          sx += (cnt > 0.f) ? (sum / cnt) : 0.f;
        }
        loss3 += sx * (1.f / 6.f);
      }
      out[0] = 10.f * loss2 + 10.f * loss3;
    }
  }
}

// ---------------- host-side numpy RandomState(seed).permutation(12)[:6] ----------------
namespace {
struct MT19937 {
  uint32_t mt[624]; int mti;
  void seed(uint32_t s) {
    mt[0] = s;
    for (int i = 1; i < 624; ++i) mt[i] = 1812433253u * (mt[i - 1] ^ (mt[i - 1] >> 30)) + (uint32_t)i;
    mti = 624;
  }
  uint32_t next() {
    if (mti >= 624) {
      for (int i = 0; i < 624; ++i) {
        uint32_t y = (mt[i] & 0x80000000u) | (mt[(i + 1) % 624] & 0x7fffffffu);
        uint32_t v = y >> 1;
        if (y & 1u) v ^= 0x9908b0dfu;
        mt[i] = mt[(i + 397) % 624] ^ v;
      }
      mti = 0;
    }
    uint32_t y = mt[mti++];
    y ^= y >> 11; y ^= (y << 7) & 0x9d2c5680u; y ^= (y << 15) & 0xefc60000u; y ^= y >> 18;
    return y;
  }
  uint32_t interval(uint32_t mx) {
    uint32_t mask = mx;
    mask |= mask >> 1; mask |= mask >> 2; mask |= mask >> 4; mask |= mask >> 8; mask |= mask >> 16;
    while (true) { uint32_t v = next() & mask; if (v <= mx) return v; }
  }
};
inline void np_perm12_first6(uint32_t seed, int* sel6) {
  int a[12]; for (int i = 0; i < 12; ++i) a[i] = i;
  MT19937 r; r.seed(seed);
  for (int i = 11; i >= 1; --i) { uint32_t j = r.interval((uint32_t)i); int t = a[i]; a[i] = a[j]; a[j] = t; }
  for (int i = 0; i < 6; ++i) sel6[i] = a[i];
}
}  // namespace

extern "C" void kernel_launch(void* const* d_in, const int* in_sizes, int n_in,
                              void* d_out, int out_size, void* d_ws, size_t ws_size,
                              hipStream_t stream) {
  const float* z1 = (const float*)d_in[0];
  const float* z2 = (const float*)d_in[1];
  float* out = (float*)d_out;

  char* base = (char*)d_ws;
  size_t off = 0;
  auto alloc = [&](size_t bytes) -> void* {
    void* p = base + off;
    off = (off + bytes + 255) & ~(size_t)255;
    return p;
  };
  unsigned short* gram   = (unsigned short*)alloc((size_t)8 * TT * TT * 2);  // 67 MB bf16 self grams
  unsigned short* zb     = (unsigned short*)alloc((size_t)8 * TT * CC * 2);
  float* sq              = (float*)alloc((size_t)8 * TT * 4);
  float* inv             = (float*)alloc((size_t)8 * TT * 4);
  int*   neigh1          = (int*)alloc((size_t)8 * TT * KK * 4);
  int*   neighC          = (int*)alloc((size_t)8 * TT * KK * 4);
  float* pmin0           = (float*)alloc((size_t)8 * 16 * TT * 4);   // per-slab row/col mins, mode0
  float* pmin1           = (float*)alloc((size_t)8 * 16 * TT * 4);   // mode1
  float* prow_v          = (float*)alloc((size_t)12 * 16 * TT * 4);
  int*   prow_i          = (int*)alloc((size_t)12 * 16 * TT * 4);
  float* pcol_v          = (float*)alloc((size_t)12 * 16 * TT * 4);
  int*   pcol_i          = (int*)alloc((size_t)12 * 16 * TT * 4);
  int*   b_of_a          = (int*)alloc((size_t)12 * TT * 4);
  int*   a_of_b          = (int*)alloc((size_t)12 * TT * 4);
  int*   idxB            = (int*)alloc((size_t)12 * TT * 4);
  int*   matchedB        = (int*)alloc((size_t)12 * TT * 4);
  int*   unmatched       = (int*)alloc((size_t)12 * TT * 4);
  int*   scalars         = (int*)alloc(12 * 16 * 4);
  float* accs            = (float*)alloc(64 * 4);

  // NRC pair selection (numpy RandomState(seed).permutation(12)[:6])
  int sel0[6], sel1[6];
  np_perm12_first6(0u, sel0);
  np_perm12_first6(1u, sel1);
  static const int PP[12] = {0, 0, 0, 1, 1, 1, 2, 2, 2, 3, 3, 3};
  static const int QQ[12] = {1, 2, 3, 0, 2, 3, 0, 1, 3, 0, 1, 2};
  PairTab tab;
  for (int d = 0; d < 2; ++d) {
    const int* sel = (d == 0) ? sel0 : sel1;
    for (int t = 0; t < 6; ++t) {
      int pi_ = PP[sel[t]], qi = QQ[sel[t]];
      int p = d * 6 + t;
      tab.sa[p] = (d == 0) ? pi_ : 4 + pi_;
      tab.sb[p] = (d == 0) ? 4 + qi : qi;
    }
  }

  // transpose-dedup (zero hits for these seeds but harmless)
  PairTab gtab; PairMap pm; int nU = 0;
  for (int p = 0; p < 12; ++p) {
    int f = -1, ftr = 0;
    for (int q = 0; q < nU; ++q) {
      if (gtab.sa[q] == tab.sb[p] && gtab.sb[q] == tab.sa[p]) { f = q; ftr = 1; break; }
      if (gtab.sa[q] == tab.sa[p] && gtab.sb[q] == tab.sb[p]) { f = q; ftr = 0; break; }
    }
    if (f >= 0) { pm.src[p] = f; pm.tr[p] = ftr; }
    else { gtab.sa[nU] = tab.sa[p]; gtab.sb[nU] = tab.sb[p]; pm.src[p] = nU; pm.tr[p] = 0; ++nU; }
  }

  // fused prep (bf16 convert + norms + acc/ticket zeroing)
  prep_kernel<<<8 * TT, 192, 0, stream>>>(z1, z2, zb, sq, inv, accs);

  // fused gram (self then cross), per-region XCD-chunked block swizzle inside the kernel
  unsigned int crossN = (unsigned int)(nU * 256);
  gram_all<<<N_SELF_BLK + crossN, 256, 0, stream>>>(crossN, zb, gram, sq, inv, gtab,
                                                    prow_v, prow_i, pcol_v, pcol_i, pmin0, pmin1);

  // fused top5 (slab-skipping threshold scan) + argmin stage 2
  top5_argmin_fused<<<4096 + 192, 256, 0, stream>>>(gram, sq, inv, pmin0, pmin1, neigh1, neighC,
                                                    prow_v, prow_i, pcol_v, pcol_i, pm, b_of_a, a_of_b);

  // mutual matching (tiny; only dependency of nrc not yet satisfied)
  mutual_only<<<12, 256, 0, stream>>>(b_of_a, a_of_b, idxB, matchedB, unmatched, scalars);

  // cb hinge + nrc hinge co-resident, with folded last-block final combine
  cb_nrc_fused<<<256 + 384, 256, 0, stream>>>(gram, inv, neigh1, neighC, idxB, unmatched, scalars,
                                              tab, accs, out);
}